// Round 17
// baseline (720.244 us; speedup 1.0000x reference)
//
#include <hip/hip_runtime.h>
#include <hip/hip_bf16.h>

typedef __bf16 bf16;
typedef __bf16 bf16x8 __attribute__((ext_vector_type(8)));
typedef __bf16 bf16x4 __attribute__((ext_vector_type(4)));
typedef __bf16 bf16x2 __attribute__((ext_vector_type(2)));
typedef float f32x4 __attribute__((ext_vector_type(4)));

#define BATCH 32
#define N_ID 1024
#define L_IN 512

static const long ACT_E = (long)BATCH * N_ID * L_IN;   // 16,777,216
static const long S_NL  = (long)N_ID * L_IN;           // 524288
static const long S_TT  = (long)N_ID * N_ID;           // 1048576

__device__ __forceinline__ void gload16(const bf16* g, bf16* l)
{
    __builtin_amdgcn_global_load_lds((__attribute__((address_space(1))) void*)g,
                                     (__attribute__((address_space(3))) void*)l, 16, 0, 0);
}

#define VM3 asm volatile("s_waitcnt vmcnt(3)" ::: "memory")
#define VM9 asm volatile("s_waitcnt vmcnt(9)" ::: "memory")
#define VM0 asm volatile("s_waitcnt vmcnt(0)" ::: "memory")
#define BAR __builtin_amdgcn_s_barrier()

// ---------------------------------------------------------------------------
// 256x128 BK=32 double-buffered counted-vmcnt NT GEMM.
// EPI: 1 bf16=acc+biasRow[m]; 3 bf16=acc;
//      6 bf16=exp2((acc+vp)*scale), vp = K-row·vbar computed INLINE from the
//            B fragments (vbar passed via biasCol); rowsum partial -> slot
//            Rbuf[z*sBR + rr*nsl + by*2+wn]
//      8 bf16=acc/Rsum(slots by col)*scal2[0]+scal2[1]  (space PV)
// ---------------------------------------------------------------------------
#define COMPUTE(CIDX, KT) \
    { \
      const bf16* pa = ldsb + (CIDX) * 12288; \
      const bf16* pb = pa + 8192; \
      bf16x8 af[4], bfv[4]; \
_Pragma("unroll") \
      for (int i = 0; i < 4; ++i) \
        af[i] = *(const bf16x8*)(pa + (wm * 64 + i * 16 + fr) * 32 + slotk); \
_Pragma("unroll") \
      for (int j = 0; j < 4; ++j) \
        bfv[j] = *(const bf16x8*)(pb + (wn * 64 + j * 16 + fr) * 32 + slotk); \
      if constexpr (EPI == 6) { \
        const float* vb = biasCol + (KT) * 32 + kg * 8; \
_Pragma("unroll") \
        for (int e = 0; e < 8; ++e) { \
          const float vbe = vb[e]; \
_Pragma("unroll") \
          for (int j = 0; j < 4; ++j) vp[j] += (float)bfv[j][e] * vbe; \
        } \
      } \
      __builtin_amdgcn_s_setprio(1); \
_Pragma("unroll") \
      for (int i = 0; i < 4; ++i) \
_Pragma("unroll") \
        for (int j = 0; j < 4; ++j) \
          acc[i][j] = __builtin_amdgcn_mfma_f32_16x16x32_bf16(af[i], bfv[j], acc[i][j], 0, 0, 0); \
      __builtin_amdgcn_s_setprio(0); \
    }

#define STAGE(CIDX, KT) { stgA(ldsb + (CIDX) * 12288, KT); \
                          stgB(ldsb + (CIDX) * 12288 + 8192, KT); }

template<int EPI>
__global__ __launch_bounds__(512, 4)
void gemm3(const bf16* __restrict__ A, const bf16* __restrict__ Bm, void* __restrict__ Cout,
           const float* __restrict__ biasCol, const float* __restrict__ biasRow,
           const void* __restrict__ Res, const float* __restrict__ scal2,
           float scale, int K,
           long lda, long ldb, long ldc,
           long sA, long sB, long sC, long sRes, long sBR, long sVp, int nsl,
           unsigned gy, unsigned gxy, unsigned nwg)
{
    __shared__ __align__(16) bf16 ldsbuf[2 * 12288];   // 48 KB
    bf16* ldsb = ldsbuf;

    unsigned id = blockIdx.x;
    {
        const unsigned q = nwg >> 3, r = nwg & 7;
        const unsigned xcd = id & 7, off = id >> 3;
        id = (xcd < r ? xcd * (q + 1) : r * (q + 1) + (xcd - r) * q) + off;
    }
    const unsigned bz = id / gxy;
    const unsigned rem = id - bz * gxy;
    const unsigned bx = rem / gy;
    const unsigned by = rem - bx * gy;

    const int t = threadIdx.x;
    const int w = t >> 6;
    const int lane = t & 63;
    const int fr = lane & 15;
    const int kg = lane >> 4;
    const int wm = w >> 1, wn = w & 1;   // 4 M x 2 N
    const long z = bz;
    const long m0 = (long)bx * 256;
    const long n0 = (long)by * 128;
    const bf16* Ab = A + z * sA;
    const bf16* Bb = Bm + z * sB;

    const int srow = w * 16 + (lane >> 2);
    const int gc = (lane & 3) ^ ((lane >> 3) & 3);
    const int slotk = (kg ^ ((fr >> 1) & 3)) * 8;

    auto stgA = [&](bf16* dst, int kt) {
#pragma unroll
        for (int r = 0; r < 2; ++r) {
            const int row = r * 128 + srow;
            gload16(Ab + (m0 + row) * lda + kt * 32 + gc * 8, dst + row * 32 + (lane & 3) * 8);
        }
    };
    auto stgB = [&](bf16* dst, int kt) {
        gload16(Bb + (n0 + srow) * ldb + kt * 32 + gc * 8, dst + srow * 32 + (lane & 3) * 8);
    };

    f32x4 acc[4][4] = {};
    float vp[4] = {0.f, 0.f, 0.f, 0.f};

    const int NT = K >> 5;
    STAGE(0, 0); STAGE(1, 1);

    for (int kt = 0; kt < NT - 1; ++kt) {
        VM3; BAR;
        COMPUTE(kt & 1, kt);
        BAR;
        if (kt + 2 < NT) STAGE(kt & 1, kt + 2);
    }
    VM0; BAR;
    COMPUTE((NT - 1) & 1, NT - 1);

    float e0 = 0.f, e1 = 0.f;
    if constexpr (EPI == 8) { e0 = scal2[0]; e1 = scal2[1]; }

    float rs[16];
    if constexpr (EPI == 6) {
        // complete vp: reduce partial k-slices across kg lanes (bits 4,5)
#pragma unroll
        for (int j = 0; j < 4; ++j) {
            vp[j] += __shfl_xor(vp[j], 16);
            vp[j] += __shfl_xor(vp[j], 32);
        }
#pragma unroll
        for (int vv = 0; vv < 16; ++vv) rs[vv] = 0.f;
    }

#pragma unroll
    for (int i = 0; i < 4; ++i) {
        const long rb = m0 + wm * 64 + i * 16 + kg * 4;
#pragma unroll
        for (int j = 0; j < 4; ++j) {
            const long cc = n0 + wn * 64 + j * 16 + fr;
            float cinv = 0.f;
            if constexpr (EPI == 8) {
                float s = 0.f;
#pragma unroll
                for (int k8 = 0; k8 < 8; ++k8) s += biasCol[z * sBR + cc * 8 + k8];
                cinv = 1.f / s;
            }
#pragma unroll
            for (int r = 0; r < 4; ++r) {
                const long rr = rb + r;
                const float v = acc[i][j][r];
                const long idx = z * sC + rr * ldc + cc;
                if constexpr (EPI == 1)      ((bf16*)Cout)[idx] = (bf16)(v + biasRow[rr]);
                else if constexpr (EPI == 3) ((bf16*)Cout)[idx] = (bf16)v;
                else if constexpr (EPI == 6) {
                    const float e = __builtin_amdgcn_exp2f((v + vp[j]) * scale);
                    ((bf16*)Cout)[idx] = (bf16)e;
                    rs[i * 4 + r] += e;
                }
                else /* 8 */                 ((bf16*)Cout)[idx] = (bf16)(v * cinv * e0 + e1);
            }
        }
    }

    if constexpr (EPI == 6) {
#pragma unroll
        for (int vv = 0; vv < 16; ++vv) {
            rs[vv] += __shfl_xor(rs[vv], 1);
            rs[vv] += __shfl_xor(rs[vv], 2);
            rs[vv] += __shfl_xor(rs[vv], 4);
            rs[vv] += __shfl_xor(rs[vv], 8);
        }
        if (fr == 0) {
            float* Rs = (float*)biasRow + z * sBR;
            const int slot = (int)by * 2 + wn;
#pragma unroll
            for (int i = 0; i < 4; ++i)
#pragma unroll
                for (int r = 0; r < 4; ++r) {
                    const long rr = m0 + wm * 64 + i * 16 + kg * 4 + r;
                    Rs[rr * nsl + slot] = rs[i * 4 + r];
                }
        }
    }
}

// ---------------------------------------------------------------------------
// Fused PV + softmax-normalize + residual + bias + LayerNorm (r15-proven).
// Tile: 64 rows x 512 cols (block owns complete rows), K=1024, 4 waves,
// 2 blocks/CU. preLN = acc/Rsum + Res + biasP; out = LN(preLN)*g+beta.
// ---------------------------------------------------------------------------
template<int OUTF32>
__global__ __launch_bounds__(256, 2)
void pvln(const bf16* __restrict__ P, const bf16* __restrict__ V,
          void* __restrict__ Out,
          const float* __restrict__ biasP, const float* __restrict__ Rslots,
          const bf16* __restrict__ Res,
          const float* __restrict__ g, const float* __restrict__ beta,
          unsigned nwg)
{
    __shared__ __align__(16) bf16 lds[2][18432];  // per buf: A 64x32 + B 512x32
    __shared__ float red[64][4][2];

    unsigned id = blockIdx.x;
    {
        const unsigned q = nwg >> 3, r = nwg & 7;
        const unsigned xcd = id & 7, off = id >> 3;
        id = (xcd < r ? xcd * (q + 1) : r * (q + 1) + (xcd - r) * q) + off;
    }
    const long z = id >> 4;
    const int m0 = (int)(id & 15) * 64;

    const int t = threadIdx.x;
    const int w = t >> 6;          // N-wave 0..3
    const int lane = t & 63;
    const int fr = lane & 15;
    const int kg = lane >> 4;

    const bf16* Ab = P + z * S_TT + (long)m0 * 1024;
    const bf16* Bb = V + z * S_NL;

    const int srow = t >> 2;                      // 0..63
    const int gc = (t & 3) ^ ((t >> 3) & 3);      // swizzled global chunk
    const int slotk = (kg ^ ((fr >> 1) & 3)) * 8;

    auto stg = [&](int buf, int kt) {
        gload16(Ab + (long)srow * 1024 + kt * 32 + gc * 8,
                &lds[buf][srow * 32 + (t & 3) * 8]);
#pragma unroll
        for (int p0 = 0; p0 < 8; ++p0) {
            const int row = p0 * 64 + srow;
            gload16(Bb + (long)row * 1024 + kt * 32 + gc * 8,
                    &lds[buf][2048 + row * 32 + (t & 3) * 8]);
        }
    };

    f32x4 acc[4][8] = {};

    stg(0, 0); stg(1, 1);
#define PVCOMP(CIDX) \
    { \
      const bf16* pa = &lds[CIDX][0]; \
      const bf16* pb = &lds[CIDX][2048]; \
      bf16x8 af[4], bfv[8]; \
_Pragma("unroll") \
      for (int i = 0; i < 4; ++i) \
        af[i] = *(const bf16x8*)(pa + (i * 16 + fr) * 32 + slotk); \
_Pragma("unroll") \
      for (int j = 0; j < 8; ++j) \
        bfv[j] = *(const bf16x8*)(pb + (w * 128 + j * 16 + fr) * 32 + slotk); \
      __builtin_amdgcn_s_setprio(1); \
_Pragma("unroll") \
      for (int i = 0; i < 4; ++i) \
_Pragma("unroll") \
        for (int j = 0; j < 8; ++j) \
          acc[i][j] = __builtin_amdgcn_mfma_f32_16x16x32_bf16(af[i], bfv[j], acc[i][j], 0, 0, 0); \
      __builtin_amdgcn_s_setprio(0); \
    }

    for (int kt = 0; kt < 31; ++kt) {
        VM9; BAR;
        PVCOMP(kt & 1);
        BAR;
        if (kt + 2 < 32) stg(kt & 1, kt + 2);
    }
    VM0; BAR;
    PVCOMP(1);

    // 1/Rsum per row (16 slots, fr-butterfly)
    float rin[16];
#pragma unroll
    for (int i = 0; i < 4; ++i)
#pragma unroll
        for (int r = 0; r < 4; ++r) {
            float s = Rslots[z * 16384 + (long)(m0 + i * 16 + kg * 4 + r) * 16 + fr];
            s += __shfl_xor(s, 1); s += __shfl_xor(s, 2);
            s += __shfl_xor(s, 4); s += __shfl_xor(s, 8);
            rin[i * 4 + r] = 1.f / s;
        }

    // preLN into acc; per-row partial sums
    float s1[16] = {}, s2[16] = {};
#pragma unroll
    for (int i = 0; i < 4; ++i)
#pragma unroll
        for (int j = 0; j < 8; ++j) {
            const int col = w * 128 + j * 16 + fr;
            const float bp = biasP[col];
#pragma unroll
            for (int r = 0; r < 4; ++r) {
                const int row = i * 16 + kg * 4 + r;
                float v = acc[i][j][r] * rin[i * 4 + r]
                        + (float)Res[z * S_NL + (long)(m0 + row) * 512 + col] + bp;
                acc[i][j][r] = v;
                s1[i * 4 + r] += v;
                s2[i * 4 + r] += v * v;
            }
        }

#pragma unroll
    for (int vv = 0; vv < 16; ++vv) {
        s1[vv] += __shfl_xor(s1[vv], 1); s2[vv] += __shfl_xor(s2[vv], 1);
        s1[vv] += __shfl_xor(s1[vv], 2); s2[vv] += __shfl_xor(s2[vv], 2);
        s1[vv] += __shfl_xor(s1[vv], 4); s2[vv] += __shfl_xor(s2[vv], 4);
        s1[vv] += __shfl_xor(s1[vv], 8); s2[vv] += __shfl_xor(s2[vv], 8);
    }
    __syncthreads();
    if (fr == 0) {
#pragma unroll
        for (int i = 0; i < 4; ++i)
#pragma unroll
            for (int r = 0; r < 4; ++r) {
                const int row = i * 16 + kg * 4 + r;
                red[row][w][0] = s1[i * 4 + r];
                red[row][w][1] = s2[i * 4 + r];
            }
    }
    __syncthreads();

    float mean[16], rstd[16];
#pragma unroll
    for (int i = 0; i < 4; ++i)
#pragma unroll
        for (int r = 0; r < 4; ++r) {
            const int row = i * 16 + kg * 4 + r;
            const float S1 = red[row][0][0] + red[row][1][0] + red[row][2][0] + red[row][3][0];
            const float S2 = red[row][0][1] + red[row][1][1] + red[row][2][1] + red[row][3][1];
            const float m = S1 * (1.f / 512.f);
            mean[i * 4 + r] = m;
            rstd[i * 4 + r] = rsqrtf(S2 * (1.f / 512.f) - m * m + 1e-5f);
        }

#pragma unroll
    for (int i = 0; i < 4; ++i)
#pragma unroll
        for (int j = 0; j < 8; ++j) {
            const int col = w * 128 + j * 16 + fr;
            const float gg = g[col], bb = beta[col];
#pragma unroll
            for (int r = 0; r < 4; ++r) {
                const int row = i * 16 + kg * 4 + r;
                const float o = (acc[i][j][r] - mean[i * 4 + r]) * rstd[i * 4 + r] * gg + bb;
                const long idx = (z * 1024 + m0 + row) * 512 + col;
                if constexpr (OUTF32) ((float*)Out)[idx] = o;
                else                  ((bf16*)Out)[idx] = (bf16)o;
            }
        }
}

// ---------------------------------------------------------------------------
__global__ __launch_bounds__(256)
void transpose_cvt(const float* __restrict__ x, bf16* __restrict__ Xb, bf16* __restrict__ xt)
{
    __shared__ bf16 tile[32][33];
    const int b = blockIdx.z;
    const int n0 = blockIdx.x * 32, l0 = blockIdx.y * 32;
    const long base = (long)b * N_ID * L_IN;
    const int tx = threadIdx.x, ty = threadIdx.y;
#pragma unroll
    for (int i = ty; i < 32; i += 8) {
        const long idx = base + (long)(n0 + i) * L_IN + l0 + tx;
        const bf16 s = (bf16)x[idx];
        Xb[idx] = s;
        tile[i][tx] = s;
    }
    __syncthreads();
#pragma unroll
    for (int i = ty; i < 32; i += 8)
        xt[base + (long)(l0 + i) * N_ID + n0 + tx] = tile[tx][i];
}

struct T6 { const float* s[6]; bf16* d[6]; };

__global__ __launch_bounds__(256)
void transpose512_6(T6 p)
{
    __shared__ bf16 tile[32][33];
    const float* src = p.s[blockIdx.z];
    bf16* dst = p.d[blockIdx.z];
    const int c0 = blockIdx.x * 32, r0 = blockIdx.y * 32;
    const int tx = threadIdx.x, ty = threadIdx.y;
#pragma unroll
    for (int i = ty; i < 32; i += 8)
        tile[i][tx] = (bf16)src[(long)(r0 + i) * 512 + c0 + tx];
    __syncthreads();
#pragma unroll
    for (int i = ty; i < 32; i += 8)
        dst[(long)(c0 + i) * 512 + r0 + tx] = tile[tx][i];
}

template<int N>
__global__ __launch_bounds__(256)
void transpose_mat(const float* __restrict__ a, const float* __restrict__ b,
                   bf16* __restrict__ da, bf16* __restrict__ db)
{
    __shared__ bf16 tile[32][33];
    const float* src = blockIdx.z ? b : a;
    bf16* dst = blockIdx.z ? db : da;
    const int c0 = blockIdx.x * 32, r0 = blockIdx.y * 32;
    const int tx = threadIdx.x, ty = threadIdx.y;
#pragma unroll
    for (int i = ty; i < 32; i += 8)
        tile[i][tx] = (bf16)src[(long)(r0 + i) * N + c0 + tx];
    __syncthreads();
#pragma unroll
    for (int i = ty; i < 32; i += 8)
        dst[(long)(c0 + i) * N + r0 + tx] = tile[tx][i];
}

__global__ void cvt_one(const float* __restrict__ s, bf16* __restrict__ d, int n)
{
    const int i = (blockIdx.x * 256 + threadIdx.x) * 4;
    if (i < n) {
        f32x4 v = *(const f32x4*)(s + i);
        bf16x4 o; o[0] = (bf16)v[0]; o[1] = (bf16)v[1]; o[2] = (bf16)v[2]; o[3] = (bf16)v[3];
        *(bf16x4*)(d + i) = o;
    }
}

__global__ void wo_sum2(const float* __restrict__ a, const float* __restrict__ b,
                        bf16* __restrict__ da, bf16* __restrict__ db)
{
    const int i = blockIdx.x * 256 + threadIdx.x;
    const float* src = blockIdx.y ? b : a;
    bf16* dst = blockIdx.y ? db : da;
    const float* p = src + (long)i * 8;
    float s = 0.f;
#pragma unroll
    for (int h = 0; h < 8; ++h) s += p[h];
    dst[i] = (bf16)s;
}

__global__ __launch_bounds__(64)
void biasfold2(const bf16* __restrict__ WsA, const float* __restrict__ bvA, const float* __restrict__ boA, float* __restrict__ outA,
               const bf16* __restrict__ WsB, const float* __restrict__ bvB, const float* __restrict__ boB, float* __restrict__ outB)
{
    const bf16* Ws = blockIdx.y ? WsB : WsA;
    const float* bv = blockIdx.y ? bvB : bvA;
    const float* bo = blockIdx.y ? boB : boA;
    float* out = blockIdx.y ? outB : outA;
    const int o = blockIdx.x;
    float s = 0.f;
    for (int l = threadIdx.x; l < 512; l += 64)
        s += (float)Ws[(long)o * 512 + l] * bv[l];
#pragma unroll
    for (int off = 32; off > 0; off >>= 1) s += __shfl_xor(s, off);
    if (threadIdx.x == 0) out[o] = bo[o] + s;
}

__global__ __launch_bounds__(64)
void vbarfold(const bf16* WkTrT, const float* tbq, float* vbarT,
              const bf16* WkTrC, const float* cbq, float* vbarC,
              const bf16* sWkTr, const float* sbq, float* vbarS,
              const float* sW1, const float* sb1, float* scal)
{
    const int o = blockIdx.x;
    const int y = blockIdx.y;
    if (y == 3) {
        if (o == 0 && threadIdx.x == 0) {
            float s = 0.f;
            for (int h = 0; h < 8; ++h) s += sW1[h];
            scal[0] = s; scal[1] = sb1[0];
        }
        return;
    }
    const bf16* W; const float* b; float* out; int D;
    if (y == 0)      { if (o >= 512) return; W = WkTrT; b = tbq; out = vbarT; D = 512; }
    else if (y == 1) { if (o >= 512) return; W = WkTrC; b = cbq; out = vbarC; D = 512; }
    else             { W = sWkTr; b = sbq; out = vbarS; D = 1024; }
    float s = 0.f;
    for (int a = threadIdx.x; a < D; a += 64)
        s += (float)W[(long)o * D + a] * b[a];
#pragma unroll
    for (int off = 32; off > 0; off >>= 1) s += __shfl_xor(s, off);
    if (threadIdx.x == 0) out[o] = s;
}

// ---------------------------------------------------------------------------
static void launch_gemm(int epi, const bf16* A, const bf16* B, void* C,
                        const float* bc, const float* br, const void* res, const float* sc2,
                        float scale, int M, int N, int K,
                        long lda, long ldb, long ldc,
                        long sA, long sB, long sC, long sRes, long sBR, long sVp, int nsl,
                        int batches, hipStream_t st)
{
    const unsigned gx = M / 256, gy = N / 128;
    const unsigned gxy = gx * gy, nwg = gxy * (unsigned)batches;
    dim3 g(nwg), blk(512);
    switch (epi) {
    case 1: gemm3<1><<<g, blk, 0, st>>>(A, B, C, bc, br, res, sc2, scale, K, lda, ldb, ldc, sA, sB, sC, sRes, sBR, sVp, nsl, gy, gxy, nwg); break;
    case 3: gemm3<3><<<g, blk, 0, st>>>(A, B, C, bc, br, res, sc2, scale, K, lda, ldb, ldc, sA, sB, sC, sRes, sBR, sVp, nsl, gy, gxy, nwg); break;
    case 6: gemm3<6><<<g, blk, 0, st>>>(A, B, C, bc, br, res, sc2, scale, K, lda, ldb, ldc, sA, sB, sC, sRes, sBR, sVp, nsl, gy, gxy, nwg); break;
    default: gemm3<8><<<g, blk, 0, st>>>(A, B, C, bc, br, res, sc2, scale, K, lda, ldb, ldc, sA, sB, sC, sRes, sBR, sVp, nsl, gy, gxy, nwg); break;
    }
}

extern "C" void kernel_launch(void* const* d_in, const int* in_sizes, int n_in,
                              void* d_out, int out_size, void* d_ws, size_t ws_size,
                              hipStream_t stream)
{
    (void)in_sizes; (void)n_in; (void)out_size;

    const float* x   = (const float*)d_in[0];
    const float* tWq = (const float*)d_in[1];  const float* tbq = (const float*)d_in[2];
    const float* tWk = (const float*)d_in[3];
    const float* tWv = (const float*)d_in[5];  const float* tbv = (const float*)d_in[6];
    const float* tWo = (const float*)d_in[7];  const float* tbo = (const float*)d_in[8];
    const float* tg  = (const float*)d_in[9];  const float* tb  = (const float*)d_in[10];
    const float* cWq = (const float*)d_in[11]; const float* cbq = (const float*)d_in[12];
    const float* cWk = (const float*)d_in[13];
    const float* cWv = (const float*)d_in[15]; const float* cbv = (const float*)d_in[16];
    const float* cWo = (const float*)d_in[17]; const float* cbo = (const float*)d_in[18];
    const float* cg  = (const float*)d_in[19]; const float* cb  = (const float*)d_in[20];
    const float* sWq = (const float*)d_in[21]; const float* sbq = (const float*)d_in[22];
    const float* sWk = (const float*)d_in[23];
    const float* sWv = (const float*)d_in[25]; const float* sbv = (const float*)d_in[26];
    const float* sW1 = (const float*)d_in[27]; const float* sb1 = (const float*)d_in[28];
    // key biases (d_in[4,14,24]) cancel in softmax

    char* p = (char*)d_ws;
    auto alloc = [&](size_t bytes) -> char* {
        char* r = p; p += (bytes + 255) & ~(size_t)255; return r;
    };

    bf16* WsT   = (bf16*)alloc(262144 * 2);
    bf16* WsC   = (bf16*)alloc(262144 * 2);
    bf16* WkTrT = (bf16*)alloc(262144 * 2);
    bf16* WkTrC = (bf16*)alloc(262144 * 2);
    bf16* WvTrT = (bf16*)alloc(262144 * 2);
    bf16* WvTrC = (bf16*)alloc(262144 * 2);
    bf16* WqTrT = (bf16*)alloc(262144 * 2);
    bf16* WqTrC = (bf16*)alloc(262144 * 2);
    bf16* WvWT  = (bf16*)alloc(262144 * 2);
    bf16* WvWC  = (bf16*)alloc(262144 * 2);
    bf16* MTt   = (bf16*)alloc(262144 * 2);
    bf16* MTc   = (bf16*)alloc(262144 * 2);
    bf16* sWqTr = (bf16*)alloc(1048576 * 2);
    bf16* sWkTr = (bf16*)alloc(1048576 * 2);
    bf16* MTs   = (bf16*)alloc(1048576 * 2);
    bf16* WvS   = (bf16*)alloc(1048576 * 2);
    float* scal  = (float*)alloc(256);
    float* biasT = (float*)alloc(512 * 4);
    float* biasC = (float*)alloc(512 * 4);
    float* vbarT = (float*)alloc(512 * 4);
    float* vbarC = (float*)alloc(512 * 4);
    float* vbarS = (float*)alloc(1024 * 4);

    const size_t ACT_B = (size_t)ACT_E * 2;
    bf16* bufG = (bf16*)alloc(ACT_B);
    bf16* Xb   = (bf16*)alloc(ACT_B);
    bf16* TO   = (bf16*)alloc(ACT_B);
    bf16* xt   = (bf16*)alloc(ACT_B);
    bf16* bufV = (bf16*)alloc(ACT_B);
    float* Rbuf = (float*)alloc((size_t)BATCH * 1024 * 16 * 4);

    size_t used = (size_t)(p - (char*)d_ws);
    int CB = 32;
    while (CB > 1 && used + (size_t)CB * 2097152ULL + 4096 > ws_size) CB >>= 1;
    bf16* Sbuf = (bf16*)alloc((size_t)CB * 2097152ULL);
    bf16* Pbuf = Sbuf;

    const float L2E = 1.4426950408889634f;
    const float rsc_t2 = 0.08838834764831845f * L2E;
    const float rsc_s2 = 0.125f * L2E;

    // ---- prep ----
    T6 tj;
    tj.s[0] = tWv; tj.s[1] = cWv; tj.s[2] = tWq; tj.s[3] = cWq; tj.s[4] = tWk; tj.s[5] = cWk;
    tj.d[0] = WvTrT; tj.d[1] = WvTrC; tj.d[2] = WqTrT; tj.d[3] = WqTrC; tj.d[4] = WkTrT; tj.d[5] = WkTrC;
    transpose512_6<<<dim3(16, 16, 6), dim3(32, 8), 0, stream>>>(tj);
    transpose_mat<1024><<<dim3(32, 32, 2), dim3(32, 8), 0, stream>>>(sWq, sWk, sWqTr, sWkTr);
    cvt_one<<<dim3(1024), dim3(256), 0, stream>>>(sWv, WvS, 1048576);
    wo_sum2<<<dim3(1024, 2), dim3(256), 0, stream>>>(tWo, cWo, WsT, WsC);
    biasfold2<<<dim3(512, 2), dim3(64), 0, stream>>>(WsT, tbv, tbo, biasT, WsC, cbv, cbo, biasC);
    vbarfold<<<dim3(1024, 4), dim3(64), 0, stream>>>(WkTrT, tbq, vbarT, WkTrC, cbq, vbarC,
                                                     sWkTr, sbq, vbarS, sW1, sb1, scal);
    launch_gemm(3, WsT, WvTrT, WvWT, nullptr, nullptr, nullptr, nullptr, 0.f,
                512, 512, 512, 512, 512, 512, 262144, 262144, 262144, 0, 0, 0, 0, 4, stream);
    launch_gemm(3, sWkTr, sWqTr, MTs, nullptr, nullptr, nullptr, nullptr, 0.f,
                1024, 1024, 1024, 1024, 1024, 1024, 0, 0, 0, 0, 0, 0, 0, 1, stream);
    transpose_cvt<<<dim3(32, 16, BATCH), dim3(32, 8), 0, stream>>>(x, Xb, xt);

    // ==== Stage T (time de_att) ====
    launch_gemm(3, Xb, MTt, bufG, nullptr, nullptr, nullptr, nullptr, 0.f,
                32768, 512, 512, 512, 512, 512, 0, 0, 0, 0, 0, 0, 0, 1, stream);
    launch_gemm(3, WvWT, Xb, bufV, nullptr, nullptr, nullptr, nullptr, 0.f,
                512, 1024, 512, 512, 512, 1024, 0, S_NL, S_NL, 0, 0, 0, 0, BATCH, stream);
    for (int c0 = 0; c0 < BATCH; c0 += CB) {
        const long off = (long)c0 * S_NL;
        launch_gemm(6, bufG + off, Xb + off, Sbuf, vbarT, Rbuf, nullptr, nullptr, rsc_t2,
                    1024, 1024, 512, 512, 512, 1024, S_NL, S_NL, S_TT, 0, 16384, 0, 16, CB, stream);
        pvln<0><<<dim3(CB * 16), dim3(256), 0, stream>>>(Sbuf, bufV + off, TO + off,
                                                         biasT, Rbuf, Xb + off, tg, tb, CB * 16);
    }

    // ==== Stage S (space attention) ====
    bf16* SOp = Xb;   // Xb dead after stage T -> space_out
    launch_gemm(3, xt, MTs, bufG, nullptr, nullptr, nullptr, nullptr, 0.f,
                16384, 1024, 1024, 1024, 1024, 1024, 0, 0, 0, 0, 0, 0, 0, 1, stream);
    launch_gemm(1, WvS, xt, bufV, nullptr, sbv, nullptr, nullptr, 0.f,
                1024, 512, 1024, 1024, 1024, 512, 0, S_NL, S_NL, 0, 0, 0, 0, BATCH, stream);
    for (int c0 = 0; c0 < BATCH; c0 += CB) {
        const long off = (long)c0 * S_NL;
        launch_gemm(6, bufG + off, xt + off, Sbuf, vbarS, Rbuf, nullptr, nullptr, rsc_s2,
                    512, 512, 1024, 1024, 1024, 512, S_NL, S_NL, (long)L_IN * L_IN, 0, 4096, 0, 8, CB, stream);
        launch_gemm(8, bufV + off, Pbuf, SOp + off, Rbuf, nullptr, nullptr, scal, 0.f,
                    1024, 512, 512, 512, 512, 512, S_NL, (long)L_IN * L_IN, S_NL, 0, 4096, 0, 8, CB, stream);
    }

    // ==== Stage C (cross de_att) ====
    launch_gemm(3, Xb, MTc, bufG, nullptr, nullptr, nullptr, nullptr, 0.f,
                32768, 512, 512, 512, 512, 512, 0, 0, 0, 0, 0, 0, 0, 1, stream);
    launch_gemm(3, WvWC, TO, bufV, nullptr, nullptr, nullptr, nullptr, 0.f,
                512, 1024, 512, 512, 512, 1024, 0, S_NL, S_NL, 0, 0, 0, 0, BATCH, stream);
    for (int c0 = 0; c0 < BATCH; c0 += CB) {
        const long off = (long)c0 * S_NL;
        launch_gemm(6, bufG + off, TO + off, Sbuf, vbarC, Rbuf, nullptr, nullptr, rsc_t2,
                    1024, 1024, 512, 512, 512, 1024, S_NL, S_NL, S_TT, 0, 16384, 0, 16, CB, stream);
        pvln<1><<<dim3(CB * 16), dim3(256), 0, stream>>>(Sbuf, bufV + off, (float*)d_out + off,
                                                         biasC, Rbuf, TO + off, cg, cb, CB * 16);
    }
}

// Round 18
// 630.860 us; speedup vs baseline: 1.1417x; 1.1417x over previous
//
#include <hip/hip_runtime.h>
#include <hip/hip_bf16.h>

typedef __bf16 bf16;
typedef __bf16 bf16x8 __attribute__((ext_vector_type(8)));
typedef __bf16 bf16x4 __attribute__((ext_vector_type(4)));
typedef __bf16 bf16x2 __attribute__((ext_vector_type(2)));
typedef float f32x4 __attribute__((ext_vector_type(4)));

#define BATCH 32
#define N_ID 1024
#define L_IN 512

static const long ACT_E = (long)BATCH * N_ID * L_IN;   // 16,777,216
static const long S_NL  = (long)N_ID * L_IN;           // 524288
static const long S_TT  = (long)N_ID * N_ID;           // 1048576

__device__ __forceinline__ void gload16(const bf16* g, bf16* l)
{
    __builtin_amdgcn_global_load_lds((__attribute__((address_space(1))) void*)g,
                                     (__attribute__((address_space(3))) void*)l, 16, 0, 0);
}

#define VM3 asm volatile("s_waitcnt vmcnt(3)" ::: "memory")
#define VM9 asm volatile("s_waitcnt vmcnt(9)" ::: "memory")
#define VM0 asm volatile("s_waitcnt vmcnt(0)" ::: "memory")
#define BAR __builtin_amdgcn_s_barrier()

// ---------------------------------------------------------------------------
// 256x128 BK=32 double-buffered counted-vmcnt NT GEMM (r15-proven).
// EPI: 1 bf16=acc+biasRow[m]; 3 bf16=acc;
//      6 bf16=exp2(acc*scale + vpre[z*sVp+cc]); rowsum partial -> slot
//            Rbuf[z*sBR + rr*nsl + by*2+wn]  (written once, no atomics)
//      8 bf16=acc/Rsum(slots by col)*scal2[0]+scal2[1]  (space PV)
// ---------------------------------------------------------------------------
#define COMPUTE(CIDX) \
    { \
      const bf16* pa = ldsb + (CIDX) * 12288; \
      const bf16* pb = pa + 8192; \
      bf16x8 af[4], bfv[4]; \
_Pragma("unroll") \
      for (int i = 0; i < 4; ++i) \
        af[i] = *(const bf16x8*)(pa + (wm * 64 + i * 16 + fr) * 32 + slotk); \
_Pragma("unroll") \
      for (int j = 0; j < 4; ++j) \
        bfv[j] = *(const bf16x8*)(pb + (wn * 64 + j * 16 + fr) * 32 + slotk); \
      __builtin_amdgcn_s_setprio(1); \
_Pragma("unroll") \
      for (int i = 0; i < 4; ++i) \
_Pragma("unroll") \
        for (int j = 0; j < 4; ++j) \
          acc[i][j] = __builtin_amdgcn_mfma_f32_16x16x32_bf16(af[i], bfv[j], acc[i][j], 0, 0, 0); \
      __builtin_amdgcn_s_setprio(0); \
    }

#define STAGE(CIDX, KT) { stgA(ldsb + (CIDX) * 12288, KT); \
                          stgB(ldsb + (CIDX) * 12288 + 8192, KT); }

template<int EPI>
__global__ __launch_bounds__(512, 4)
void gemm3(const bf16* __restrict__ A, const bf16* __restrict__ Bm, void* __restrict__ Cout,
           const float* __restrict__ biasCol, const float* __restrict__ biasRow,
           const void* __restrict__ Res, const float* __restrict__ scal2,
           float scale, int K,
           long lda, long ldb, long ldc,
           long sA, long sB, long sC, long sRes, long sBR, long sVp, int nsl,
           unsigned gy, unsigned gxy, unsigned nwg)
{
    __shared__ __align__(16) bf16 ldsbuf[2 * 12288];   // 48 KB
    bf16* ldsb = ldsbuf;

    unsigned id = blockIdx.x;
    {
        const unsigned q = nwg >> 3, r = nwg & 7;
        const unsigned xcd = id & 7, off = id >> 3;
        id = (xcd < r ? xcd * (q + 1) : r * (q + 1) + (xcd - r) * q) + off;
    }
    const unsigned bz = id / gxy;
    const unsigned rem = id - bz * gxy;
    const unsigned bx = rem / gy;
    const unsigned by = rem - bx * gy;

    const int t = threadIdx.x;
    const int w = t >> 6;
    const int lane = t & 63;
    const int fr = lane & 15;
    const int kg = lane >> 4;
    const int wm = w >> 1, wn = w & 1;   // 4 M x 2 N
    const long z = bz;
    const long m0 = (long)bx * 256;
    const long n0 = (long)by * 128;
    const bf16* Ab = A + z * sA;
    const bf16* Bb = Bm + z * sB;

    const int srow = w * 16 + (lane >> 2);
    const int gc = (lane & 3) ^ ((lane >> 3) & 3);
    const int slotk = (kg ^ ((fr >> 1) & 3)) * 8;

    auto stgA = [&](bf16* dst, int kt) {
#pragma unroll
        for (int r = 0; r < 2; ++r) {
            const int row = r * 128 + srow;
            gload16(Ab + (m0 + row) * lda + kt * 32 + gc * 8, dst + row * 32 + (lane & 3) * 8);
        }
    };
    auto stgB = [&](bf16* dst, int kt) {
        gload16(Bb + (n0 + srow) * ldb + kt * 32 + gc * 8, dst + srow * 32 + (lane & 3) * 8);
    };

    f32x4 acc[4][4] = {};

    const int NT = K >> 5;
    STAGE(0, 0); STAGE(1, 1);

    for (int kt = 0; kt < NT - 1; ++kt) {
        VM3; BAR;
        COMPUTE(kt & 1);
        BAR;
        if (kt + 2 < NT) STAGE(kt & 1, kt + 2);
    }
    VM0; BAR;
    COMPUTE((NT - 1) & 1);

    float e0 = 0.f, e1 = 0.f;
    if constexpr (EPI == 8) { e0 = scal2[0]; e1 = scal2[1]; }

    float rs[16];
    if constexpr (EPI == 6) {
#pragma unroll
        for (int vv = 0; vv < 16; ++vv) rs[vv] = 0.f;
    }

#pragma unroll
    for (int i = 0; i < 4; ++i) {
        const long rb = m0 + wm * 64 + i * 16 + kg * 4;
#pragma unroll
        for (int j = 0; j < 4; ++j) {
            const long cc = n0 + wn * 64 + j * 16 + fr;
            float cinv = 0.f, vj = 0.f;
            if constexpr (EPI == 8) {
                float s = 0.f;
#pragma unroll
                for (int k8 = 0; k8 < 8; ++k8) s += biasCol[z * sBR + cc * 8 + k8];
                cinv = 1.f / s;
            }
            if constexpr (EPI == 6) vj = biasCol[z * sVp + cc];
#pragma unroll
            for (int r = 0; r < 4; ++r) {
                const long rr = rb + r;
                const float v = acc[i][j][r];
                const long idx = z * sC + rr * ldc + cc;
                if constexpr (EPI == 1)      ((bf16*)Cout)[idx] = (bf16)(v + biasRow[rr]);
                else if constexpr (EPI == 3) ((bf16*)Cout)[idx] = (bf16)v;
                else if constexpr (EPI == 6) {
                    const float e = __builtin_amdgcn_exp2f(v * scale + vj);
                    ((bf16*)Cout)[idx] = (bf16)e;
                    rs[i * 4 + r] += e;
                }
                else /* 8 */                 ((bf16*)Cout)[idx] = (bf16)(v * cinv * e0 + e1);
            }
        }
    }

    if constexpr (EPI == 6) {
#pragma unroll
        for (int vv = 0; vv < 16; ++vv) {
            rs[vv] += __shfl_xor(rs[vv], 1);
            rs[vv] += __shfl_xor(rs[vv], 2);
            rs[vv] += __shfl_xor(rs[vv], 4);
            rs[vv] += __shfl_xor(rs[vv], 8);
        }
        if (fr == 0) {
            float* Rs = (float*)biasRow + z * sBR;
            const int slot = (int)by * 2 + wn;
#pragma unroll
            for (int i = 0; i < 4; ++i)
#pragma unroll
                for (int r = 0; r < 4; ++r) {
                    const long rr = m0 + wm * 64 + i * 16 + kg * 4 + r;
                    Rs[rr * nsl + slot] = rs[i * 4 + r];
                }
        }
    }
}

// ---------------------------------------------------------------------------
// Fused PV + softmax-normalize + residual + bias + LayerNorm (r15-proven).
// Tile: 64 rows x 512 cols (block owns complete rows), K=1024, 4 waves,
// 2 blocks/CU. preLN = acc/Rsum + Res + biasP; out = LN(preLN)*g+beta.
// ---------------------------------------------------------------------------
template<int OUTF32>
__global__ __launch_bounds__(256, 2)
void pvln(const bf16* __restrict__ P, const bf16* __restrict__ V,
          void* __restrict__ Out,
          const float* __restrict__ biasP, const float* __restrict__ Rslots,
          const bf16* __restrict__ Res,
          const float* __restrict__ g, const float* __restrict__ beta,
          unsigned nwg)
{
    __shared__ __align__(16) bf16 lds[2][18432];  // per buf: A 64x32 + B 512x32
    __shared__ float red[64][4][2];

    unsigned id = blockIdx.x;
    {
        const unsigned q = nwg >> 3, r = nwg & 7;
        const unsigned xcd = id & 7, off = id >> 3;
        id = (xcd < r ? xcd * (q + 1) : r * (q + 1) + (xcd - r) * q) + off;
    }
    const long z = id >> 4;
    const int m0 = (int)(id & 15) * 64;

    const int t = threadIdx.x;
    const int w = t >> 6;          // N-wave 0..3
    const int lane = t & 63;
    const int fr = lane & 15;
    const int kg = lane >> 4;

    const bf16* Ab = P + z * S_TT + (long)m0 * 1024;
    const bf16* Bb = V + z * S_NL;

    const int srow = t >> 2;                      // 0..63
    const int gc = (t & 3) ^ ((t >> 3) & 3);      // swizzled global chunk
    const int slotk = (kg ^ ((fr >> 1) & 3)) * 8;

    auto stg = [&](int buf, int kt) {
        gload16(Ab + (long)srow * 1024 + kt * 32 + gc * 8,
                &lds[buf][srow * 32 + (t & 3) * 8]);
#pragma unroll
        for (int p0 = 0; p0 < 8; ++p0) {
            const int row = p0 * 64 + srow;
            gload16(Bb + (long)row * 1024 + kt * 32 + gc * 8,
                    &lds[buf][2048 + row * 32 + (t & 3) * 8]);
        }
    };

    f32x4 acc[4][8] = {};

    stg(0, 0); stg(1, 1);
#define PVCOMP(CIDX) \
    { \
      const bf16* pa = &lds[CIDX][0]; \
      const bf16* pb = &lds[CIDX][2048]; \
      bf16x8 af[4], bfv[8]; \
_Pragma("unroll") \
      for (int i = 0; i < 4; ++i) \
        af[i] = *(const bf16x8*)(pa + (i * 16 + fr) * 32 + slotk); \
_Pragma("unroll") \
      for (int j = 0; j < 8; ++j) \
        bfv[j] = *(const bf16x8*)(pb + (w * 128 + j * 16 + fr) * 32 + slotk); \
      __builtin_amdgcn_s_setprio(1); \
_Pragma("unroll") \
      for (int i = 0; i < 4; ++i) \
_Pragma("unroll") \
        for (int j = 0; j < 8; ++j) \
          acc[i][j] = __builtin_amdgcn_mfma_f32_16x16x32_bf16(af[i], bfv[j], acc[i][j], 0, 0, 0); \
      __builtin_amdgcn_s_setprio(0); \
    }

    for (int kt = 0; kt < 31; ++kt) {
        VM9; BAR;
        PVCOMP(kt & 1);
        BAR;
        if (kt + 2 < 32) stg(kt & 1, kt + 2);
    }
    VM0; BAR;
    PVCOMP(1);

    // 1/Rsum per row (16 slots, fr-butterfly)
    float rin[16];
#pragma unroll
    for (int i = 0; i < 4; ++i)
#pragma unroll
        for (int r = 0; r < 4; ++r) {
            float s = Rslots[z * 16384 + (long)(m0 + i * 16 + kg * 4 + r) * 16 + fr];
            s += __shfl_xor(s, 1); s += __shfl_xor(s, 2);
            s += __shfl_xor(s, 4); s += __shfl_xor(s, 8);
            rin[i * 4 + r] = 1.f / s;
        }

    // preLN into acc; per-row partial sums
    float s1[16] = {}, s2[16] = {};
#pragma unroll
    for (int i = 0; i < 4; ++i)
#pragma unroll
        for (int j = 0; j < 8; ++j) {
            const int col = w * 128 + j * 16 + fr;
            const float bp = biasP[col];
#pragma unroll
            for (int r = 0; r < 4; ++r) {
                const int row = i * 16 + kg * 4 + r;
                float v = acc[i][j][r] * rin[i * 4 + r]
                        + (float)Res[z * S_NL + (long)(m0 + row) * 512 + col] + bp;
                acc[i][j][r] = v;
                s1[i * 4 + r] += v;
                s2[i * 4 + r] += v * v;
            }
        }

#pragma unroll
    for (int vv = 0; vv < 16; ++vv) {
        s1[vv] += __shfl_xor(s1[vv], 1); s2[vv] += __shfl_xor(s2[vv], 1);
        s1[vv] += __shfl_xor(s1[vv], 2); s2[vv] += __shfl_xor(s2[vv], 2);
        s1[vv] += __shfl_xor(s1[vv], 4); s2[vv] += __shfl_xor(s2[vv], 4);
        s1[vv] += __shfl_xor(s1[vv], 8); s2[vv] += __shfl_xor(s2[vv], 8);
    }
    __syncthreads();
    if (fr == 0) {
#pragma unroll
        for (int i = 0; i < 4; ++i)
#pragma unroll
            for (int r = 0; r < 4; ++r) {
                const int row = i * 16 + kg * 4 + r;
                red[row][w][0] = s1[i * 4 + r];
                red[row][w][1] = s2[i * 4 + r];
            }
    }
    __syncthreads();

    float mean[16], rstd[16];
#pragma unroll
    for (int i = 0; i < 4; ++i)
#pragma unroll
        for (int r = 0; r < 4; ++r) {
            const int row = i * 16 + kg * 4 + r;
            const float S1 = red[row][0][0] + red[row][1][0] + red[row][2][0] + red[row][3][0];
            const float S2 = red[row][0][1] + red[row][1][1] + red[row][2][1] + red[row][3][1];
            const float m = S1 * (1.f / 512.f);
            mean[i * 4 + r] = m;
            rstd[i * 4 + r] = rsqrtf(S2 * (1.f / 512.f) - m * m + 1e-5f);
        }

#pragma unroll
    for (int i = 0; i < 4; ++i)
#pragma unroll
        for (int j = 0; j < 8; ++j) {
            const int col = w * 128 + j * 16 + fr;
            const float gg = g[col], bb = beta[col];
#pragma unroll
            for (int r = 0; r < 4; ++r) {
                const int row = i * 16 + kg * 4 + r;
                const float o = (acc[i][j][r] - mean[i * 4 + r]) * rstd[i * 4 + r] * gg + bb;
                const long idx = (z * 1024 + m0 + row) * 512 + col;
                if constexpr (OUTF32) ((float*)Out)[idx] = o;
                else                  ((bf16*)Out)[idx] = (bf16)o;
            }
        }
}

// ---------------------------------------------------------------------------
__global__ __launch_bounds__(256)
void transpose_cvt(const float* __restrict__ x, bf16* __restrict__ Xb, bf16* __restrict__ xt)
{
    __shared__ bf16 tile[32][33];
    const int b = blockIdx.z;
    const int n0 = blockIdx.x * 32, l0 = blockIdx.y * 32;
    const long base = (long)b * N_ID * L_IN;
    const int tx = threadIdx.x, ty = threadIdx.y;
#pragma unroll
    for (int i = ty; i < 32; i += 8) {
        const long idx = base + (long)(n0 + i) * L_IN + l0 + tx;
        const bf16 s = (bf16)x[idx];
        Xb[idx] = s;
        tile[i][tx] = s;
    }
    __syncthreads();
#pragma unroll
    for (int i = ty; i < 32; i += 8)
        xt[base + (long)(l0 + i) * N_ID + n0 + tx] = tile[tx][i];
}

struct T6 { const float* s[6]; bf16* d[6]; };

__global__ __launch_bounds__(256)
void transpose512_6(T6 p)
{
    __shared__ bf16 tile[32][33];
    const float* src = p.s[blockIdx.z];
    bf16* dst = p.d[blockIdx.z];
    const int c0 = blockIdx.x * 32, r0 = blockIdx.y * 32;
    const int tx = threadIdx.x, ty = threadIdx.y;
#pragma unroll
    for (int i = ty; i < 32; i += 8)
        tile[i][tx] = (bf16)src[(long)(r0 + i) * 512 + c0 + tx];
    __syncthreads();
#pragma unroll
    for (int i = ty; i < 32; i += 8)
        dst[(long)(c0 + i) * 512 + r0 + tx] = tile[tx][i];
}

template<int N>
__global__ __launch_bounds__(256)
void transpose_mat(const float* __restrict__ a, const float* __restrict__ b,
                   bf16* __restrict__ da, bf16* __restrict__ db)
{
    __shared__ bf16 tile[32][33];
    const float* src = blockIdx.z ? b : a;
    bf16* dst = blockIdx.z ? db : da;
    const int c0 = blockIdx.x * 32, r0 = blockIdx.y * 32;
    const int tx = threadIdx.x, ty = threadIdx.y;
#pragma unroll
    for (int i = ty; i < 32; i += 8)
        tile[i][tx] = (bf16)src[(long)(r0 + i) * N + c0 + tx];
    __syncthreads();
#pragma unroll
    for (int i = ty; i < 32; i += 8)
        dst[(long)(c0 + i) * N + r0 + tx] = tile[tx][i];
}

__global__ void cvt_one(const float* __restrict__ s, bf16* __restrict__ d, int n)
{
    const int i = (blockIdx.x * 256 + threadIdx.x) * 4;
    if (i < n) {
        f32x4 v = *(const f32x4*)(s + i);
        bf16x4 o; o[0] = (bf16)v[0]; o[1] = (bf16)v[1]; o[2] = (bf16)v[2]; o[3] = (bf16)v[3];
        *(bf16x4*)(d + i) = o;
    }
}

__global__ void wo_sum2(const float* __restrict__ a, const float* __restrict__ b,
                        bf16* __restrict__ da, bf16* __restrict__ db)
{
    const int i = blockIdx.x * 256 + threadIdx.x;
    const float* src = blockIdx.y ? b : a;
    bf16* dst = blockIdx.y ? db : da;
    const float* p = src + (long)i * 8;
    float s = 0.f;
#pragma unroll
    for (int h = 0; h < 8; ++h) s += p[h];
    dst[i] = (bf16)s;
}

__global__ __launch_bounds__(64)
void biasfold2(const bf16* __restrict__ WsA, const float* __restrict__ bvA, const float* __restrict__ boA, float* __restrict__ outA,
               const bf16* __restrict__ WsB, const float* __restrict__ bvB, const float* __restrict__ boB, float* __restrict__ outB)
{
    const bf16* Ws = blockIdx.y ? WsB : WsA;
    const float* bv = blockIdx.y ? bvB : bvA;
    const float* bo = blockIdx.y ? boB : boA;
    float* out = blockIdx.y ? outB : outA;
    const int o = blockIdx.x;
    float s = 0.f;
    for (int l = threadIdx.x; l < 512; l += 64)
        s += (float)Ws[(long)o * 512 + l] * bv[l];
#pragma unroll
    for (int off = 32; off > 0; off >>= 1) s += __shfl_xor(s, off);
    if (threadIdx.x == 0) out[o] = bo[o] + s;
}

__global__ __launch_bounds__(64)
void vbarfold(const bf16* WkTrT, const float* tbq, float* vbarT,
              const bf16* WkTrC, const float* cbq, float* vbarC,
              const bf16* sWkTr, const float* sbq, float* vbarS,
              const float* sW1, const float* sb1, float* scal)
{
    const int o = blockIdx.x;
    const int y = blockIdx.y;
    if (y == 3) {
        if (o == 0 && threadIdx.x == 0) {
            float s = 0.f;
            for (int h = 0; h < 8; ++h) s += sW1[h];
            scal[0] = s; scal[1] = sb1[0];
        }
        return;
    }
    const bf16* W; const float* b; float* out; int D;
    if (y == 0)      { if (o >= 512) return; W = WkTrT; b = tbq; out = vbarT; D = 512; }
    else if (y == 1) { if (o >= 512) return; W = WkTrC; b = cbq; out = vbarC; D = 512; }
    else             { W = sWkTr; b = sbq; out = vbarS; D = 1024; }
    float s = 0.f;
    for (int a = threadIdx.x; a < D; a += 64)
        s += (float)W[(long)o * D + a] * b[a];
#pragma unroll
    for (int off = 32; off > 0; off >>= 1) s += __shfl_xor(s, off);
    if (threadIdx.x == 0) out[o] = s;
}

// two vrow jobs (T: Xb D=512 -> outT; S: xt D=1024 -> outS) in one launch
__global__ __launch_bounds__(256)
void vrow2(const bf16* __restrict__ Xb, const float* __restrict__ vbT, float* __restrict__ outT, float scT,
           const bf16* __restrict__ xt, const float* __restrict__ vbS, float* __restrict__ outS, float scS)
{
    const int lane = threadIdx.x & 63;
    if (blockIdx.y == 0) {
        const long row = (long)blockIdx.x * 4 + (threadIdx.x >> 6);
        const bf16* r = Xb + row * 512;
        bf16x8 xv = *(const bf16x8*)(r + lane * 8);
        const float* vb = vbT + lane * 8;
        float s = 0.f;
#pragma unroll
        for (int e = 0; e < 8; ++e) s += (float)xv[e] * vb[e];
#pragma unroll
        for (int o = 32; o > 0; o >>= 1) s += __shfl_xor(s, o);
        if (lane == 0) outT[row] = s * scT;
    } else {
        if (blockIdx.x >= 4096) return;
        const long row = (long)blockIdx.x * 4 + (threadIdx.x >> 6);
        const bf16* r = xt + row * 1024;
        float s = 0.f;
#pragma unroll
        for (int u = 0; u < 2; ++u) {
            bf16x8 xv = *(const bf16x8*)(r + u * 512 + lane * 8);
            const float* vb = vbS + u * 512 + lane * 8;
#pragma unroll
            for (int e = 0; e < 8; ++e) s += (float)xv[e] * vb[e];
        }
#pragma unroll
        for (int o = 32; o > 0; o >>= 1) s += __shfl_xor(s, o);
        if (lane == 0) outS[row] = s * scS;
    }
}

template<int D>
__global__ __launch_bounds__(256)
void vrow(const bf16* __restrict__ Src, const float* __restrict__ vbar,
          float* __restrict__ out, float scale2)
{
    const long row = (long)blockIdx.x * 4 + (threadIdx.x >> 6);
    const int lane = threadIdx.x & 63;
    const bf16* r = Src + row * D;
    float s = 0.f;
#pragma unroll
    for (int u = 0; u < D / 512; ++u) {
        bf16x8 xv = *(const bf16x8*)(r + u * 512 + lane * 8);
        const float* vb = vbar + u * 512 + lane * 8;
#pragma unroll
        for (int e = 0; e < 8; ++e) s += (float)xv[e] * vb[e];
    }
#pragma unroll
    for (int o = 32; o > 0; o >>= 1) s += __shfl_xor(s, o);
    if (lane == 0) out[row] = s * scale2;
}

// ---------------------------------------------------------------------------
static void launch_gemm(int epi, const bf16* A, const bf16* B, void* C,
                        const float* bc, const float* br, const void* res, const float* sc2,
                        float scale, int M, int N, int K,
                        long lda, long ldb, long ldc,
                        long sA, long sB, long sC, long sRes, long sBR, long sVp, int nsl,
                        int batches, hipStream_t st)
{
    const unsigned gx = M / 256, gy = N / 128;
    const unsigned gxy = gx * gy, nwg = gxy * (unsigned)batches;
    dim3 g(nwg), blk(512);
    switch (epi) {
    case 1: gemm3<1><<<g, blk, 0, st>>>(A, B, C, bc, br, res, sc2, scale, K, lda, ldb, ldc, sA, sB, sC, sRes, sBR, sVp, nsl, gy, gxy, nwg); break;
    case 3: gemm3<3><<<g, blk, 0, st>>>(A, B, C, bc, br, res, sc2, scale, K, lda, ldb, ldc, sA, sB, sC, sRes, sBR, sVp, nsl, gy, gxy, nwg); break;
    case 6: gemm3<6><<<g, blk, 0, st>>>(A, B, C, bc, br, res, sc2, scale, K, lda, ldb, ldc, sA, sB, sC, sRes, sBR, sVp, nsl, gy, gxy, nwg); break;
    default: gemm3<8><<<g, blk, 0, st>>>(A, B, C, bc, br, res, sc2, scale, K, lda, ldb, ldc, sA, sB, sC, sRes, sBR, sVp, nsl, gy, gxy, nwg); break;
    }
}

extern "C" void kernel_launch(void* const* d_in, const int* in_sizes, int n_in,
                              void* d_out, int out_size, void* d_ws, size_t ws_size,
                              hipStream_t stream)
{
    (void)in_sizes; (void)n_in; (void)out_size;

    const float* x   = (const float*)d_in[0];
    const float* tWq = (const float*)d_in[1];  const float* tbq = (const float*)d_in[2];
    const float* tWk = (const float*)d_in[3];
    const float* tWv = (const float*)d_in[5];  const float* tbv = (const float*)d_in[6];
    const float* tWo = (const float*)d_in[7];  const float* tbo = (const float*)d_in[8];
    const float* tg  = (const float*)d_in[9];  const float* tb  = (const float*)d_in[10];
    const float* cWq = (const float*)d_in[11]; const float* cbq = (const float*)d_in[12];
    const float* cWk = (const float*)d_in[13];
    const float* cWv = (const float*)d_in[15]; const float* cbv = (const float*)d_in[16];
    const float* cWo = (const float*)d_in[17]; const float* cbo = (const float*)d_in[18];
    const float* cg  = (const float*)d_in[19]; const float* cb  = (const float*)d_in[20];
    const float* sWq = (const float*)d_in[21]; const float* sbq = (const float*)d_in[22];
    const float* sWk = (const float*)d_in[23];
    const float* sWv = (const float*)d_in[25]; const float* sbv = (const float*)d_in[26];
    const float* sW1 = (const float*)d_in[27]; const float* sb1 = (const float*)d_in[28];
    // key biases (d_in[4,14,24]) cancel in softmax

    char* p = (char*)d_ws;
    auto alloc = [&](size_t bytes) -> char* {
        char* r = p; p += (bytes + 255) & ~(size_t)255; return r;
    };

    bf16* WsT   = (bf16*)alloc(262144 * 2);
    bf16* WsC   = (bf16*)alloc(262144 * 2);
    bf16* WkTrT = (bf16*)alloc(262144 * 2);
    bf16* WkTrC = (bf16*)alloc(262144 * 2);
    bf16* WvTrT = (bf16*)alloc(262144 * 2);
    bf16* WvTrC = (bf16*)alloc(262144 * 2);
    bf16* WqTrT = (bf16*)alloc(262144 * 2);
    bf16* WqTrC = (bf16*)alloc(262144 * 2);
    bf16* WvWT  = (bf16*)alloc(262144 * 2);
    bf16* WvWC  = (bf16*)alloc(262144 * 2);
    bf16* MTt   = (bf16*)alloc(262144 * 2);
    bf16* MTc   = (bf16*)alloc(262144 * 2);
    bf16* sWqTr = (bf16*)alloc(1048576 * 2);
    bf16* sWkTr = (bf16*)alloc(1048576 * 2);
    bf16* MTs   = (bf16*)alloc(1048576 * 2);
    bf16* WvS   = (bf16*)alloc(1048576 * 2);
    float* scal  = (float*)alloc(256);
    float* biasT = (float*)alloc(512 * 4);
    float* biasC = (float*)alloc(512 * 4);
    float* vbarT = (float*)alloc(512 * 4);
    float* vbarC = (float*)alloc(512 * 4);
    float* vbarS = (float*)alloc(1024 * 4);

    const size_t ACT_B = (size_t)ACT_E * 2;
    bf16* bufG = (bf16*)alloc(ACT_B);
    bf16* Xb   = (bf16*)alloc(ACT_B);
    bf16* TO   = (bf16*)alloc(ACT_B);
    bf16* xt   = (bf16*)alloc(ACT_B);
    bf16* bufV = (bf16*)alloc(ACT_B);
    float* vpreT = (float*)alloc(BATCH * 1024 * 4);
    float* vpreS = (float*)alloc(BATCH * 512 * 4);
    float* Rbuf = (float*)alloc((size_t)BATCH * 1024 * 16 * 4);

    size_t used = (size_t)(p - (char*)d_ws);
    int CB = 32;
    while (CB > 1 && used + (size_t)CB * 2097152ULL + 4096 > ws_size) CB >>= 1;
    bf16* Sbuf = (bf16*)alloc((size_t)CB * 2097152ULL);
    bf16* Pbuf = Sbuf;

    const float L2E = 1.4426950408889634f;
    const float rsc_t2 = 0.08838834764831845f * L2E;
    const float rsc_s2 = 0.125f * L2E;

    // ---- prep ----
    T6 tj;
    tj.s[0] = tWv; tj.s[1] = cWv; tj.s[2] = tWq; tj.s[3] = cWq; tj.s[4] = tWk; tj.s[5] = cWk;
    tj.d[0] = WvTrT; tj.d[1] = WvTrC; tj.d[2] = WqTrT; tj.d[3] = WqTrC; tj.d[4] = WkTrT; tj.d[5] = WkTrC;
    transpose512_6<<<dim3(16, 16, 6), dim3(32, 8), 0, stream>>>(tj);
    transpose_mat<1024><<<dim3(32, 32, 2), dim3(32, 8), 0, stream>>>(sWq, sWk, sWqTr, sWkTr);
    cvt_one<<<dim3(1024), dim3(256), 0, stream>>>(sWv, WvS, 1048576);
    wo_sum2<<<dim3(1024, 2), dim3(256), 0, stream>>>(tWo, cWo, WsT, WsC);
    biasfold2<<<dim3(512, 2), dim3(64), 0, stream>>>(WsT, tbv, tbo, biasT, WsC, cbv, cbo, biasC);
    vbarfold<<<dim3(1024, 4), dim3(64), 0, stream>>>(WkTrT, tbq, vbarT, WkTrC, cbq, vbarC,
                                                     sWkTr, sbq, vbarS, sW1, sb1, scal);
    launch_gemm(3, WsT, WvTrT, WvWT, nullptr, nullptr, nullptr, nullptr, 0.f,
                512, 512, 512, 512, 512, 512, 262144, 262144, 262144, 0, 0, 0, 0, 4, stream);
    launch_gemm(3, sWkTr, sWqTr, MTs, nullptr, nullptr, nullptr, nullptr, 0.f,
                1024, 1024, 1024, 1024, 1024, 1024, 0, 0, 0, 0, 0, 0, 0, 1, stream);
    transpose_cvt<<<dim3(32, 16, BATCH), dim3(32, 8), 0, stream>>>(x, Xb, xt);
    vrow2<<<dim3(8192, 2), dim3(256), 0, stream>>>(Xb, vbarT, vpreT, rsc_t2, xt, vbarS, vpreS, rsc_s2);

    // ==== Stage T (time de_att) ====
    launch_gemm(3, Xb, MTt, bufG, nullptr, nullptr, nullptr, nullptr, 0.f,
                32768, 512, 512, 512, 512, 512, 0, 0, 0, 0, 0, 0, 0, 1, stream);
    launch_gemm(3, WvWT, Xb, bufV, nullptr, nullptr, nullptr, nullptr, 0.f,
                512, 1024, 512, 512, 512, 1024, 0, S_NL, S_NL, 0, 0, 0, 0, BATCH, stream);
    for (int c0 = 0; c0 < BATCH; c0 += CB) {
        const long off = (long)c0 * S_NL;
        launch_gemm(6, bufG + off, Xb + off, Sbuf, vpreT + (long)c0 * 1024, Rbuf, nullptr, nullptr, rsc_t2,
                    1024, 1024, 512, 512, 512, 1024, S_NL, S_NL, S_TT, 0, 16384, 1024, 16, CB, stream);
        pvln<0><<<dim3(CB * 16), dim3(256), 0, stream>>>(Sbuf, bufV + off, TO + off,
                                                         biasT, Rbuf, Xb + off, tg, tb, CB * 16);
    }

    // ==== Stage S (space attention) ====
    bf16* SOp = Xb;   // Xb dead after stage T -> space_out
    launch_gemm(3, xt, MTs, bufG, nullptr, nullptr, nullptr, nullptr, 0.f,
                16384, 1024, 1024, 1024, 1024, 1024, 0, 0, 0, 0, 0, 0, 0, 1, stream);
    launch_gemm(1, WvS, xt, bufV, nullptr, sbv, nullptr, nullptr, 0.f,
                1024, 512, 1024, 1024, 1024, 512, 0, S_NL, S_NL, 0, 0, 0, 0, BATCH, stream);
    for (int c0 = 0; c0 < BATCH; c0 += CB) {
        const long off = (long)c0 * S_NL;
        launch_gemm(6, bufG + off, xt + off, Sbuf, vpreS + (long)c0 * 512, Rbuf, nullptr, nullptr, rsc_s2,
                    512, 512, 1024, 1024, 1024, 512, S_NL, S_NL, (long)L_IN * L_IN, 0, 4096, 512, 8, CB, stream);
        launch_gemm(8, bufV + off, Pbuf, SOp + off, Rbuf, nullptr, nullptr, scal, 0.f,
                    1024, 512, 512, 512, 512, 512, S_NL, (long)L_IN * L_IN, S_NL, 0, 4096, 0, 8, CB, stream);
    }

    // ==== Stage C (cross de_att) ====
    launch_gemm(3, Xb, MTc, bufG, nullptr, nullptr, nullptr, nullptr, 0.f,
                32768, 512, 512, 512, 512, 512, 0, 0, 0, 0, 0, 0, 0, 1, stream);
    launch_gemm(3, WvWC, TO, bufV, nullptr, nullptr, nullptr, nullptr, 0.f,
                512, 1024, 512, 512, 512, 1024, 0, S_NL, S_NL, 0, 0, 0, 0, BATCH, stream);
    vrow<512><<<dim3(8192), dim3(256), 0, stream>>>(TO, vbarC, vpreT, rsc_t2);
    for (int c0 = 0; c0 < BATCH; c0 += CB) {
        const long off = (long)c0 * S_NL;
        launch_gemm(6, bufG + off, TO + off, Sbuf, vpreT + (long)c0 * 1024, Rbuf, nullptr, nullptr, rsc_t2,
                    1024, 1024, 512, 512, 512, 1024, S_NL, S_NL, S_TT, 0, 16384, 1024, 16, CB, stream);
        pvln<1><<<dim3(CB * 16), dim3(256), 0, stream>>>(Sbuf, bufV + off, (float*)d_out + off,
                                                         biasC, Rbuf, TO + off, cg, cb, CB * 16);
    }
}

// Round 19
// 609.546 us; speedup vs baseline: 1.1816x; 1.0350x over previous
//
#include <hip/hip_runtime.h>
#include <hip/hip_bf16.h>

typedef __bf16 bf16;
typedef __bf16 bf16x8 __attribute__((ext_vector_type(8)));
typedef __bf16 bf16x4 __attribute__((ext_vector_type(4)));
typedef __bf16 bf16x2 __attribute__((ext_vector_type(2)));
typedef float f32x4 __attribute__((ext_vector_type(4)));

#define BATCH 32
#define N_ID 1024
#define L_IN 512

static const long ACT_E = (long)BATCH * N_ID * L_IN;   // 16,777,216
static const long S_NL  = (long)N_ID * L_IN;           // 524288
static const long S_TT  = (long)N_ID * N_ID;           // 1048576

__device__ __forceinline__ void gload16(const bf16* g, bf16* l)
{
    __builtin_amdgcn_global_load_lds((__attribute__((address_space(1))) void*)g,
                                     (__attribute__((address_space(3))) void*)l, 16, 0, 0);
}

#define VM3 asm volatile("s_waitcnt vmcnt(3)" ::: "memory")
#define VM5 asm volatile("s_waitcnt vmcnt(5)" ::: "memory")
#define VM0 asm volatile("s_waitcnt vmcnt(0)" ::: "memory")
#define BAR __builtin_amdgcn_s_barrier()

// ---------------------------------------------------------------------------
// 256x128 BK=32 double-buffered counted-vmcnt NT GEMM (r15-proven).
// EPI: 1 bf16=acc+biasRow[m]; 3 bf16=acc;
//      6 bf16=exp2(acc*scale + vpre[z*sVp+cc]); rowsum partial -> slot
//      8 bf16=acc/Rsum(slots by col)*scal2[0]+scal2[1]  (space PV)
// ---------------------------------------------------------------------------
#define COMPUTE(CIDX) \
    { \
      const bf16* pa = ldsb + (CIDX) * 12288; \
      const bf16* pb = pa + 8192; \
      bf16x8 af[4], bfv[4]; \
_Pragma("unroll") \
      for (int i = 0; i < 4; ++i) \
        af[i] = *(const bf16x8*)(pa + (wm * 64 + i * 16 + fr) * 32 + slotk); \
_Pragma("unroll") \
      for (int j = 0; j < 4; ++j) \
        bfv[j] = *(const bf16x8*)(pb + (wn * 64 + j * 16 + fr) * 32 + slotk); \
      __builtin_amdgcn_s_setprio(1); \
_Pragma("unroll") \
      for (int i = 0; i < 4; ++i) \
_Pragma("unroll") \
        for (int j = 0; j < 4; ++j) \
          acc[i][j] = __builtin_amdgcn_mfma_f32_16x16x32_bf16(af[i], bfv[j], acc[i][j], 0, 0, 0); \
      __builtin_amdgcn_s_setprio(0); \
    }

#define STAGE(CIDX, KT) { stgA(ldsb + (CIDX) * 12288, KT); \
                          stgB(ldsb + (CIDX) * 12288 + 8192, KT); }

template<int EPI>
__global__ __launch_bounds__(512, 4)
void gemm3(const bf16* __restrict__ A, const bf16* __restrict__ Bm, void* __restrict__ Cout,
           const float* __restrict__ biasCol, const float* __restrict__ biasRow,
           const void* __restrict__ Res, const float* __restrict__ scal2,
           float scale, int K,
           long lda, long ldb, long ldc,
           long sA, long sB, long sC, long sRes, long sBR, long sVp, int nsl,
           unsigned gy, unsigned gxy, unsigned nwg)
{
    __shared__ __align__(16) bf16 ldsbuf[2 * 12288];   // 48 KB
    bf16* ldsb = ldsbuf;

    unsigned id = blockIdx.x;
    {
        const unsigned q = nwg >> 3, r = nwg & 7;
        const unsigned xcd = id & 7, off = id >> 3;
        id = (xcd < r ? xcd * (q + 1) : r * (q + 1) + (xcd - r) * q) + off;
    }
    const unsigned bz = id / gxy;
    const unsigned rem = id - bz * gxy;
    const unsigned bx = rem / gy;
    const unsigned by = rem - bx * gy;

    const int t = threadIdx.x;
    const int w = t >> 6;
    const int lane = t & 63;
    const int fr = lane & 15;
    const int kg = lane >> 4;
    const int wm = w >> 1, wn = w & 1;   // 4 M x 2 N
    const long z = bz;
    const long m0 = (long)bx * 256;
    const long n0 = (long)by * 128;
    const bf16* Ab = A + z * sA;
    const bf16* Bb = Bm + z * sB;

    const int srow = w * 16 + (lane >> 2);
    const int gc = (lane & 3) ^ ((lane >> 3) & 3);
    const int slotk = (kg ^ ((fr >> 1) & 3)) * 8;

    auto stgA = [&](bf16* dst, int kt) {
#pragma unroll
        for (int r = 0; r < 2; ++r) {
            const int row = r * 128 + srow;
            gload16(Ab + (m0 + row) * lda + kt * 32 + gc * 8, dst + row * 32 + (lane & 3) * 8);
        }
    };
    auto stgB = [&](bf16* dst, int kt) {
        gload16(Bb + (n0 + srow) * ldb + kt * 32 + gc * 8, dst + srow * 32 + (lane & 3) * 8);
    };

    f32x4 acc[4][4] = {};

    const int NT = K >> 5;
    STAGE(0, 0); STAGE(1, 1);

    for (int kt = 0; kt < NT - 1; ++kt) {
        VM3; BAR;
        COMPUTE(kt & 1);
        BAR;
        if (kt + 2 < NT) STAGE(kt & 1, kt + 2);
    }
    VM0; BAR;
    COMPUTE((NT - 1) & 1);

    float e0 = 0.f, e1 = 0.f;
    if constexpr (EPI == 8) { e0 = scal2[0]; e1 = scal2[1]; }

    float rs[16];
    if constexpr (EPI == 6) {
#pragma unroll
        for (int vv = 0; vv < 16; ++vv) rs[vv] = 0.f;
    }

#pragma unroll
    for (int i = 0; i < 4; ++i) {
        const long rb = m0 + wm * 64 + i * 16 + kg * 4;
#pragma unroll
        for (int j = 0; j < 4; ++j) {
            const long cc = n0 + wn * 64 + j * 16 + fr;
            float cinv = 0.f, vj = 0.f;
            if constexpr (EPI == 8) {
                float s = 0.f;
#pragma unroll
                for (int k8 = 0; k8 < 8; ++k8) s += biasCol[z * sBR + cc * 8 + k8];
                cinv = 1.f / s;
            }
            if constexpr (EPI == 6) vj = biasCol[z * sVp + cc];
#pragma unroll
            for (int r = 0; r < 4; ++r) {
                const long rr = rb + r;
                const float v = acc[i][j][r];
                const long idx = z * sC + rr * ldc + cc;
                if constexpr (EPI == 1)      ((bf16*)Cout)[idx] = (bf16)(v + biasRow[rr]);
                else if constexpr (EPI == 3) ((bf16*)Cout)[idx] = (bf16)v;
                else if constexpr (EPI == 6) {
                    const float e = __builtin_amdgcn_exp2f(v * scale + vj);
                    ((bf16*)Cout)[idx] = (bf16)e;
                    rs[i * 4 + r] += e;
                }
                else /* 8 */                 ((bf16*)Cout)[idx] = (bf16)(v * cinv * e0 + e1);
            }
        }
    }

    if constexpr (EPI == 6) {
#pragma unroll
        for (int vv = 0; vv < 16; ++vv) {
            rs[vv] += __shfl_xor(rs[vv], 1);
            rs[vv] += __shfl_xor(rs[vv], 2);
            rs[vv] += __shfl_xor(rs[vv], 4);
            rs[vv] += __shfl_xor(rs[vv], 8);
        }
        if (fr == 0) {
            float* Rs = (float*)biasRow + z * sBR;
            const int slot = (int)by * 2 + wn;
#pragma unroll
            for (int i = 0; i < 4; ++i)
#pragma unroll
                for (int r = 0; r < 4; ++r) {
                    const long rr = m0 + wm * 64 + i * 16 + kg * 4 + r;
                    Rs[rr * nsl + slot] = rs[i * 4 + r];
                }
        }
    }
}

// ---------------------------------------------------------------------------
// Fused PV + softmax-normalize + residual + bias + LayerNorm.
// Tile 64 x 512 (full width), K=1024, 512 threads / 8 waves (2M x 4N:
// wave = 32 rows x 128 cols), 2 blocks/CU -> 16 waves/CU.
// Uniform staging: every wave issues 5 gload/step (1 A-load lane<32 masked
// + 4 B-loads) -> uniform vmcnt(5). Padded reduce red[64][5][2].
// ---------------------------------------------------------------------------
template<int OUTF32>
__global__ __launch_bounds__(512, 4)
void pvln(const bf16* __restrict__ P, const bf16* __restrict__ V,
          void* __restrict__ Out,
          const float* __restrict__ biasP, const float* __restrict__ Rslots,
          const bf16* __restrict__ Res,
          const float* __restrict__ g, const float* __restrict__ beta,
          unsigned nwg)
{
    __shared__ __align__(16) bf16 lds[2][18432];  // per buf: A 64x32 + B 512x32
    __shared__ float red[64][5][2];               // padded: row stride 10 floats

    unsigned id = blockIdx.x;
    {
        const unsigned q = nwg >> 3, r = nwg & 7;
        const unsigned xcd = id & 7, off = id >> 3;
        id = (xcd < r ? xcd * (q + 1) : r * (q + 1) + (xcd - r) * q) + off;
    }
    const long z = id >> 4;
    const int m0 = (int)(id & 15) * 64;

    const int t = threadIdx.x;      // 0..511
    const int w = t >> 6;           // 0..7
    const int lane = t & 63;
    const int fr = lane & 15;
    const int kg = lane >> 4;
    const int wm = w >> 2;          // 2 M halves (32 rows each)
    const int wn = w & 3;           // 4 N slices (128 cols each)

    const bf16* Ab = P + z * S_TT + (long)m0 * 1024;
    const bf16* Bb = V + z * S_NL;

    const int srowB = t >> 2;                     // 0..127
    const int gcB = (t & 3) ^ ((t >> 3) & 3);     // B write swizzle
    const int gcA = (lane & 3) ^ (lane >> 3);     // A write swizzle (lane<32)
    const int slotk = (kg ^ ((fr >> 1) & 3)) * 8; // read slot

    auto stg = [&](int buf, int kt) {
        // A: 64 rows x 4 chunks = 256 loads; wave w covers rows w*8..w*8+7
        if (lane < 32) {
            const int row = w * 8 + (lane >> 2);
            gload16(Ab + (long)row * 1024 + kt * 32 + gcA * 8,
                    &lds[buf][row * 32 + (lane & 3) * 8]);
        }
#pragma unroll
        for (int p0 = 0; p0 < 4; ++p0) {          // B: 512 rows, 4 loads/thread
            const int row = p0 * 128 + srowB;
            gload16(Bb + (long)row * 1024 + kt * 32 + gcB * 8,
                    &lds[buf][2048 + row * 32 + (t & 3) * 8]);
        }
    };

    f32x4 acc[2][8] = {};

#define PVCOMP(CIDX) \
    { \
      const bf16* pa = &lds[CIDX][0]; \
      const bf16* pb = &lds[CIDX][2048]; \
      bf16x8 af[2]; \
_Pragma("unroll") \
      for (int i = 0; i < 2; ++i) \
        af[i] = *(const bf16x8*)(pa + (wm * 32 + i * 16 + fr) * 32 + slotk); \
_Pragma("unroll") \
      for (int jh = 0; jh < 2; ++jh) { \
        bf16x8 bfv[4]; \
_Pragma("unroll") \
        for (int jj = 0; jj < 4; ++jj) \
          bfv[jj] = *(const bf16x8*)(pb + (wn * 128 + (jh * 4 + jj) * 16 + fr) * 32 + slotk); \
        __builtin_amdgcn_s_setprio(1); \
_Pragma("unroll") \
        for (int i = 0; i < 2; ++i) \
_Pragma("unroll") \
          for (int jj = 0; jj < 4; ++jj) \
            acc[i][jh * 4 + jj] = __builtin_amdgcn_mfma_f32_16x16x32_bf16(af[i], bfv[jj], acc[i][jh * 4 + jj], 0, 0, 0); \
        __builtin_amdgcn_s_setprio(0); \
      } \
    }

    stg(0, 0); stg(1, 1);
    for (int kt = 0; kt < 31; ++kt) {
        VM5; BAR;
        PVCOMP(kt & 1);
        BAR;
        if (kt + 2 < 32) stg(kt & 1, kt + 2);
    }
    VM0; BAR;
    PVCOMP(1);

    // 1/Rsum per row (16 slots, fr-butterfly); 8 rows per thread
    float rin[8];
#pragma unroll
    for (int i = 0; i < 2; ++i)
#pragma unroll
        for (int r = 0; r < 4; ++r) {
            float s = Rslots[z * 16384 + (long)(m0 + wm * 32 + i * 16 + kg * 4 + r) * 16 + fr];
            s += __shfl_xor(s, 1); s += __shfl_xor(s, 2);
            s += __shfl_xor(s, 4); s += __shfl_xor(s, 8);
            rin[i * 4 + r] = 1.f / s;
        }

    // preLN into acc; per-row partial sums over this wave's 128 cols
    float s1[8] = {}, s2[8] = {};
#pragma unroll
    for (int i = 0; i < 2; ++i)
#pragma unroll
        for (int j = 0; j < 8; ++j) {
            const int col = wn * 128 + j * 16 + fr;
            const float bp = biasP[col];
#pragma unroll
            for (int r = 0; r < 4; ++r) {
                const int row = wm * 32 + i * 16 + kg * 4 + r;
                float v = acc[i][j][r] * rin[i * 4 + r]
                        + (float)Res[z * S_NL + (long)(m0 + row) * 512 + col] + bp;
                acc[i][j][r] = v;
                s1[i * 4 + r] += v;
                s2[i * 4 + r] += v * v;
            }
        }

#pragma unroll
    for (int vv = 0; vv < 8; ++vv) {
        s1[vv] += __shfl_xor(s1[vv], 1); s2[vv] += __shfl_xor(s2[vv], 1);
        s1[vv] += __shfl_xor(s1[vv], 2); s2[vv] += __shfl_xor(s2[vv], 2);
        s1[vv] += __shfl_xor(s1[vv], 4); s2[vv] += __shfl_xor(s2[vv], 4);
        s1[vv] += __shfl_xor(s1[vv], 8); s2[vv] += __shfl_xor(s2[vv], 8);
    }
    __syncthreads();
    if (fr == 0) {
#pragma unroll
        for (int i = 0; i < 2; ++i)
#pragma unroll
            for (int r = 0; r < 4; ++r) {
                const int row = wm * 32 + i * 16 + kg * 4 + r;
                red[row][wn][0] = s1[i * 4 + r];
                red[row][wn][1] = s2[i * 4 + r];
            }
    }
    __syncthreads();

    float mean[8], rstd[8];
#pragma unroll
    for (int i = 0; i < 2; ++i)
#pragma unroll
        for (int r = 0; r < 4; ++r) {
            const int row = wm * 32 + i * 16 + kg * 4 + r;
            const float S1 = red[row][0][0] + red[row][1][0] + red[row][2][0] + red[row][3][0];
            const float S2 = red[row][0][1] + red[row][1][1] + red[row][2][1] + red[row][3][1];
            const float m = S1 * (1.f / 512.f);
            mean[i * 4 + r] = m;
            rstd[i * 4 + r] = rsqrtf(S2 * (1.f / 512.f) - m * m + 1e-5f);
        }

#pragma unroll
    for (int i = 0; i < 2; ++i)
#pragma unroll
        for (int j = 0; j < 8; ++j) {
            const int col = wn * 128 + j * 16 + fr;
            const float gg = g[col], bb = beta[col];
#pragma unroll
            for (int r = 0; r < 4; ++r) {
                const int row = wm * 32 + i * 16 + kg * 4 + r;
                const float o = (acc[i][j][r] - mean[i * 4 + r]) * rstd[i * 4 + r] * gg + bb;
                const long idx = (z * 1024 + m0 + row) * 512 + col;
                if constexpr (OUTF32) ((float*)Out)[idx] = o;
                else                  ((bf16*)Out)[idx] = (bf16)o;
            }
        }
}

// ---------------------------------------------------------------------------
__global__ __launch_bounds__(256)
void transpose_cvt(const float* __restrict__ x, bf16* __restrict__ Xb, bf16* __restrict__ xt)
{
    __shared__ bf16 tile[32][33];
    const int b = blockIdx.z;
    const int n0 = blockIdx.x * 32, l0 = blockIdx.y * 32;
    const long base = (long)b * N_ID * L_IN;
    const int tx = threadIdx.x, ty = threadIdx.y;
#pragma unroll
    for (int i = ty; i < 32; i += 8) {
        const long idx = base + (long)(n0 + i) * L_IN + l0 + tx;
        const bf16 s = (bf16)x[idx];
        Xb[idx] = s;
        tile[i][tx] = s;
    }
    __syncthreads();
#pragma unroll
    for (int i = ty; i < 32; i += 8)
        xt[base + (long)(l0 + i) * N_ID + n0 + tx] = tile[tx][i];
}

struct T6 { const float* s[6]; bf16* d[6]; };

__global__ __launch_bounds__(256)
void transpose512_6(T6 p)
{
    __shared__ bf16 tile[32][33];
    const float* src = p.s[blockIdx.z];
    bf16* dst = p.d[blockIdx.z];
    const int c0 = blockIdx.x * 32, r0 = blockIdx.y * 32;
    const int tx = threadIdx.x, ty = threadIdx.y;
#pragma unroll
    for (int i = ty; i < 32; i += 8)
        tile[i][tx] = (bf16)src[(long)(r0 + i) * 512 + c0 + tx];
    __syncthreads();
#pragma unroll
    for (int i = ty; i < 32; i += 8)
        dst[(long)(c0 + i) * 512 + r0 + tx] = tile[tx][i];
}

template<int N>
__global__ __launch_bounds__(256)
void transpose_mat(const float* __restrict__ a, const float* __restrict__ b,
                   bf16* __restrict__ da, bf16* __restrict__ db)
{
    __shared__ bf16 tile[32][33];
    const float* src = blockIdx.z ? b : a;
    bf16* dst = blockIdx.z ? db : da;
    const int c0 = blockIdx.x * 32, r0 = blockIdx.y * 32;
    const int tx = threadIdx.x, ty = threadIdx.y;
#pragma unroll
    for (int i = ty; i < 32; i += 8)
        tile[i][tx] = (bf16)src[(long)(r0 + i) * N + c0 + tx];
    __syncthreads();
#pragma unroll
    for (int i = ty; i < 32; i += 8)
        dst[(long)(c0 + i) * N + r0 + tx] = tile[tx][i];
}

__global__ void cvt_one(const float* __restrict__ s, bf16* __restrict__ d, int n)
{
    const int i = (blockIdx.x * 256 + threadIdx.x) * 4;
    if (i < n) {
        f32x4 v = *(const f32x4*)(s + i);
        bf16x4 o; o[0] = (bf16)v[0]; o[1] = (bf16)v[1]; o[2] = (bf16)v[2]; o[3] = (bf16)v[3];
        *(bf16x4*)(d + i) = o;
    }
}

__global__ void wo_sum2(const float* __restrict__ a, const float* __restrict__ b,
                        bf16* __restrict__ da, bf16* __restrict__ db)
{
    const int i = blockIdx.x * 256 + threadIdx.x;
    const float* src = blockIdx.y ? b : a;
    bf16* dst = blockIdx.y ? db : da;
    const float* p = src + (long)i * 8;
    float s = 0.f;
#pragma unroll
    for (int h = 0; h < 8; ++h) s += p[h];
    dst[i] = (bf16)s;
}

__global__ __launch_bounds__(64)
void biasfold2(const bf16* __restrict__ WsA, const float* __restrict__ bvA, const float* __restrict__ boA, float* __restrict__ outA,
               const bf16* __restrict__ WsB, const float* __restrict__ bvB, const float* __restrict__ boB, float* __restrict__ outB)
{
    const bf16* Ws = blockIdx.y ? WsB : WsA;
    const float* bv = blockIdx.y ? bvB : bvA;
    const float* bo = blockIdx.y ? boB : boA;
    float* out = blockIdx.y ? outB : outA;
    const int o = blockIdx.x;
    float s = 0.f;
    for (int l = threadIdx.x; l < 512; l += 64)
        s += (float)Ws[(long)o * 512 + l] * bv[l];
#pragma unroll
    for (int off = 32; off > 0; off >>= 1) s += __shfl_xor(s, off);
    if (threadIdx.x == 0) out[o] = bo[o] + s;
}

__global__ __launch_bounds__(64)
void vbarfold(const bf16* WkTrT, const float* tbq, float* vbarT,
              const bf16* WkTrC, const float* cbq, float* vbarC,
              const bf16* sWkTr, const float* sbq, float* vbarS,
              const float* sW1, const float* sb1, float* scal)
{
    const int o = blockIdx.x;
    const int y = blockIdx.y;
    if (y == 3) {
        if (o == 0 && threadIdx.x == 0) {
            float s = 0.f;
            for (int h = 0; h < 8; ++h) s += sW1[h];
            scal[0] = s; scal[1] = sb1[0];
        }
        return;
    }
    const bf16* W; const float* b; float* out; int D;
    if (y == 0)      { if (o >= 512) return; W = WkTrT; b = tbq; out = vbarT; D = 512; }
    else if (y == 1) { if (o >= 512) return; W = WkTrC; b = cbq; out = vbarC; D = 512; }
    else             { W = sWkTr; b = sbq; out = vbarS; D = 1024; }
    float s = 0.f;
    for (int a = threadIdx.x; a < D; a += 64)
        s += (float)W[(long)o * D + a] * b[a];
#pragma unroll
    for (int off = 32; off > 0; off >>= 1) s += __shfl_xor(s, off);
    if (threadIdx.x == 0) out[o] = s;
}

// two vrow jobs (T: Xb D=512 -> outT; S: xt D=1024 -> outS) in one launch
__global__ __launch_bounds__(256)
void vrow2(const bf16* __restrict__ Xb, const float* __restrict__ vbT, float* __restrict__ outT, float scT,
           const bf16* __restrict__ xt, const float* __restrict__ vbS, float* __restrict__ outS, float scS)
{
    const int lane = threadIdx.x & 63;
    if (blockIdx.y == 0) {
        const long row = (long)blockIdx.x * 4 + (threadIdx.x >> 6);
        const bf16* r = Xb + row * 512;
        bf16x8 xv = *(const bf16x8*)(r + lane * 8);
        const float* vb = vbT + lane * 8;
        float s = 0.f;
#pragma unroll
        for (int e = 0; e < 8; ++e) s += (float)xv[e] * vb[e];
#pragma unroll
        for (int o = 32; o > 0; o >>= 1) s += __shfl_xor(s, o);
        if (lane == 0) outT[row] = s * scT;
    } else {
        if (blockIdx.x >= 4096) return;
        const long row = (long)blockIdx.x * 4 + (threadIdx.x >> 6);
        const bf16* r = xt + row * 1024;
        float s = 0.f;
#pragma unroll
        for (int u = 0; u < 2; ++u) {
            bf16x8 xv = *(const bf16x8*)(r + u * 512 + lane * 8);
            const float* vb = vbS + u * 512 + lane * 8;
#pragma unroll
            for (int e = 0; e < 8; ++e) s += (float)xv[e] * vb[e];
        }
#pragma unroll
        for (int o = 32; o > 0; o >>= 1) s += __shfl_xor(s, o);
        if (lane == 0) outS[row] = s * scS;
    }
}

template<int D>
__global__ __launch_bounds__(256)
void vrow(const bf16* __restrict__ Src, const float* __restrict__ vbar,
          float* __restrict__ out, float scale2)
{
    const long row = (long)blockIdx.x * 4 + (threadIdx.x >> 6);
    const int lane = threadIdx.x & 63;
    const bf16* r = Src + row * D;
    float s = 0.f;
#pragma unroll
    for (int u = 0; u < D / 512; ++u) {
        bf16x8 xv = *(const bf16x8*)(r + u * 512 + lane * 8);
        const float* vb = vbar + u * 512 + lane * 8;
#pragma unroll
        for (int e = 0; e < 8; ++e) s += (float)xv[e] * vb[e];
    }
#pragma unroll
    for (int o = 32; o > 0; o >>= 1) s += __shfl_xor(s, o);
    if (lane == 0) out[row] = s * scale2;
}

// ---------------------------------------------------------------------------
static void launch_gemm(int epi, const bf16* A, const bf16* B, void* C,
                        const float* bc, const float* br, const void* res, const float* sc2,
                        float scale, int M, int N, int K,
                        long lda, long ldb, long ldc,
                        long sA, long sB, long sC, long sRes, long sBR, long sVp, int nsl,
                        int batches, hipStream_t st)
{
    const unsigned gx = M / 256, gy = N / 128;
    const unsigned gxy = gx * gy, nwg = gxy * (unsigned)batches;
    dim3 g(nwg), blk(512);
    switch (epi) {
    case 1: gemm3<1><<<g, blk, 0, st>>>(A, B, C, bc, br, res, sc2, scale, K, lda, ldb, ldc, sA, sB, sC, sRes, sBR, sVp, nsl, gy, gxy, nwg); break;
    case 3: gemm3<3><<<g, blk, 0, st>>>(A, B, C, bc, br, res, sc2, scale, K, lda, ldb, ldc, sA, sB, sC, sRes, sBR, sVp, nsl, gy, gxy, nwg); break;
    case 6: gemm3<6><<<g, blk, 0, st>>>(A, B, C, bc, br, res, sc2, scale, K, lda, ldb, ldc, sA, sB, sC, sRes, sBR, sVp, nsl, gy, gxy, nwg); break;
    default: gemm3<8><<<g, blk, 0, st>>>(A, B, C, bc, br, res, sc2, scale, K, lda, ldb, ldc, sA, sB, sC, sRes, sBR, sVp, nsl, gy, gxy, nwg); break;
    }
}

extern "C" void kernel_launch(void* const* d_in, const int* in_sizes, int n_in,
                              void* d_out, int out_size, void* d_ws, size_t ws_size,
                              hipStream_t stream)
{
    (void)in_sizes; (void)n_in; (void)out_size;

    const float* x   = (const float*)d_in[0];
    const float* tWq = (const float*)d_in[1];  const float* tbq = (const float*)d_in[2];
    const float* tWk = (const float*)d_in[3];
    const float* tWv = (const float*)d_in[5];  const float* tbv = (const float*)d_in[6];
    const float* tWo = (const float*)d_in[7];  const float* tbo = (const float*)d_in[8];
    const float* tg  = (const float*)d_in[9];  const float* tb  = (const float*)d_in[10];
    const float* cWq = (const float*)d_in[11]; const float* cbq = (const float*)d_in[12];
    const float* cWk = (const float*)d_in[13];
    const float* cWv = (const float*)d_in[15]; const float* cbv = (const float*)d_in[16];
    const float* cWo = (const float*)d_in[17]; const float* cbo = (const float*)d_in[18];
    const float* cg  = (const float*)d_in[19]; const float* cb  = (const float*)d_in[20];
    const float* sWq = (const float*)d_in[21]; const float* sbq = (const float*)d_in[22];
    const float* sWk = (const float*)d_in[23];
    const float* sWv = (const float*)d_in[25]; const float* sbv = (const float*)d_in[26];
    const float* sW1 = (const float*)d_in[27]; const float* sb1 = (const float*)d_in[28];
    // key biases (d_in[4,14,24]) cancel in softmax

    char* p = (char*)d_ws;
    auto alloc = [&](size_t bytes) -> char* {
        char* r = p; p += (bytes + 255) & ~(size_t)255; return r;
    };

    bf16* WsT   = (bf16*)alloc(262144 * 2);
    bf16* WsC   = (bf16*)alloc(262144 * 2);
    bf16* WkTrT = (bf16*)alloc(262144 * 2);
    bf16* WkTrC = (bf16*)alloc(262144 * 2);
    bf16* WvTrT = (bf16*)alloc(262144 * 2);
    bf16* WvTrC = (bf16*)alloc(262144 * 2);
    bf16* WqTrT = (bf16*)alloc(262144 * 2);
    bf16* WqTrC = (bf16*)alloc(262144 * 2);
    bf16* WvWT  = (bf16*)alloc(262144 * 2);
    bf16* WvWC  = (bf16*)alloc(262144 * 2);
    bf16* MTt   = (bf16*)alloc(262144 * 2);
    bf16* MTc   = (bf16*)alloc(262144 * 2);
    bf16* sWqTr = (bf16*)alloc(1048576 * 2);
    bf16* sWkTr = (bf16*)alloc(1048576 * 2);
    bf16* MTs   = (bf16*)alloc(1048576 * 2);
    bf16* WvS   = (bf16*)alloc(1048576 * 2);
    float* scal  = (float*)alloc(256);
    float* biasT = (float*)alloc(512 * 4);
    float* biasC = (float*)alloc(512 * 4);
    float* vbarT = (float*)alloc(512 * 4);
    float* vbarC = (float*)alloc(512 * 4);
    float* vbarS = (float*)alloc(1024 * 4);

    const size_t ACT_B = (size_t)ACT_E * 2;
    bf16* bufG = (bf16*)alloc(ACT_B);
    bf16* Xb   = (bf16*)alloc(ACT_B);
    bf16* TO   = (bf16*)alloc(ACT_B);
    bf16* xt   = (bf16*)alloc(ACT_B);
    bf16* bufV = (bf16*)alloc(ACT_B);
    float* vpreT = (float*)alloc(BATCH * 1024 * 4);
    float* vpreS = (float*)alloc(BATCH * 512 * 4);
    float* Rbuf = (float*)alloc((size_t)BATCH * 1024 * 16 * 4);

    size_t used = (size_t)(p - (char*)d_ws);
    int CB = 32;
    while (CB > 1 && used + (size_t)CB * 2097152ULL + 4096 > ws_size) CB >>= 1;
    bf16* Sbuf = (bf16*)alloc((size_t)CB * 2097152ULL);
    bf16* Pbuf = Sbuf;

    const float L2E = 1.4426950408889634f;
    const float rsc_t2 = 0.08838834764831845f * L2E;
    const float rsc_s2 = 0.125f * L2E;

    // ---- prep ----
    T6 tj;
    tj.s[0] = tWv; tj.s[1] = cWv; tj.s[2] = tWq; tj.s[3] = cWq; tj.s[4] = tWk; tj.s[5] = cWk;
    tj.d[0] = WvTrT; tj.d[1] = WvTrC; tj.d[2] = WqTrT; tj.d[3] = WqTrC; tj.d[4] = WkTrT; tj.d[5] = WkTrC;
    transpose512_6<<<dim3(16, 16, 6), dim3(32, 8), 0, stream>>>(tj);
    transpose_mat<1024><<<dim3(32, 32, 2), dim3(32, 8), 0, stream>>>(sWq, sWk, sWqTr, sWkTr);
    cvt_one<<<dim3(1024), dim3(256), 0, stream>>>(sWv, WvS, 1048576);
    wo_sum2<<<dim3(1024, 2), dim3(256), 0, stream>>>(tWo, cWo, WsT, WsC);
    biasfold2<<<dim3(512, 2), dim3(64), 0, stream>>>(WsT, tbv, tbo, biasT, WsC, cbv, cbo, biasC);
    vbarfold<<<dim3(1024, 4), dim3(64), 0, stream>>>(WkTrT, tbq, vbarT, WkTrC, cbq, vbarC,
                                                     sWkTr, sbq, vbarS, sW1, sb1, scal);
    launch_gemm(3, WsT, WvTrT, WvWT, nullptr, nullptr, nullptr, nullptr, 0.f,
                512, 512, 512, 512, 512, 512, 262144, 262144, 262144, 0, 0, 0, 0, 4, stream);
    launch_gemm(3, sWkTr, sWqTr, MTs, nullptr, nullptr, nullptr, nullptr, 0.f,
                1024, 1024, 1024, 1024, 1024, 1024, 0, 0, 0, 0, 0, 0, 0, 1, stream);
    transpose_cvt<<<dim3(32, 16, BATCH), dim3(32, 8), 0, stream>>>(x, Xb, xt);
    vrow2<<<dim3(8192, 2), dim3(256), 0, stream>>>(Xb, vbarT, vpreT, rsc_t2, xt, vbarS, vpreS, rsc_s2);

    // ==== Stage T (time de_att) ====
    launch_gemm(3, Xb, MTt, bufG, nullptr, nullptr, nullptr, nullptr, 0.f,
                32768, 512, 512, 512, 512, 512, 0, 0, 0, 0, 0, 0, 0, 1, stream);
    launch_gemm(3, WvWT, Xb, bufV, nullptr, nullptr, nullptr, nullptr, 0.f,
                512, 1024, 512, 512, 512, 1024, 0, S_NL, S_NL, 0, 0, 0, 0, BATCH, stream);
    for (int c0 = 0; c0 < BATCH; c0 += CB) {
        const long off = (long)c0 * S_NL;
        launch_gemm(6, bufG + off, Xb + off, Sbuf, vpreT + (long)c0 * 1024, Rbuf, nullptr, nullptr, rsc_t2,
                    1024, 1024, 512, 512, 512, 1024, S_NL, S_NL, S_TT, 0, 16384, 1024, 16, CB, stream);
        pvln<0><<<dim3(CB * 16), dim3(512), 0, stream>>>(Sbuf, bufV + off, TO + off,
                                                         biasT, Rbuf, Xb + off, tg, tb, CB * 16);
    }

    // ==== Stage S (space attention) ====
    bf16* SOp = Xb;   // Xb dead after stage T -> space_out
    launch_gemm(3, xt, MTs, bufG, nullptr, nullptr, nullptr, nullptr, 0.f,
                16384, 1024, 1024, 1024, 1024, 1024, 0, 0, 0, 0, 0, 0, 0, 1, stream);
    launch_gemm(1, WvS, xt, bufV, nullptr, sbv, nullptr, nullptr, 0.f,
                1024, 512, 1024, 1024, 1024, 512, 0, S_NL, S_NL, 0, 0, 0, 0, BATCH, stream);
    for (int c0 = 0; c0 < BATCH; c0 += CB) {
        const long off = (long)c0 * S_NL;
        launch_gemm(6, bufG + off, xt + off, Sbuf, vpreS + (long)c0 * 512, Rbuf, nullptr, nullptr, rsc_s2,
                    512, 512, 1024, 1024, 1024, 512, S_NL, S_NL, (long)L_IN * L_IN, 0, 4096, 512, 8, CB, stream);
        launch_gemm(8, bufV + off, Pbuf, SOp + off, Rbuf, nullptr, nullptr, scal, 0.f,
                    1024, 512, 512, 512, 512, 512, S_NL, (long)L_IN * L_IN, S_NL, 0, 4096, 0, 8, CB, stream);
    }

    // ==== Stage C (cross de_att) ====
    launch_gemm(3, Xb, MTc, bufG, nullptr, nullptr, nullptr, nullptr, 0.f,
                32768, 512, 512, 512, 512, 512, 0, 0, 0, 0, 0, 0, 0, 1, stream);
    launch_gemm(3, WvWC, TO, bufV, nullptr, nullptr, nullptr, nullptr, 0.f,
                512, 1024, 512, 512, 512, 1024, 0, S_NL, S_NL, 0, 0, 0, 0, BATCH, stream);
    vrow<512><<<dim3(8192), dim3(256), 0, stream>>>(TO, vbarC, vpreT, rsc_t2);
    for (int c0 = 0; c0 < BATCH; c0 += CB) {
        const long off = (long)c0 * S_NL;
        launch_gemm(6, bufG + off, TO + off, Sbuf, vpreT + (long)c0 * 1024, Rbuf, nullptr, nullptr, rsc_t2,
                    1024, 1024, 512, 512, 512, 1024, S_NL, S_NL, S_TT, 0, 16384, 1024, 16, CB, stream);
        pvln<1><<<dim3(CB * 16), dim3(512), 0, stream>>>(Sbuf, bufV + off, (float*)d_out + off,
                                                         biasC, Rbuf, TO + off, cg, cb, CB * 16);
    }
}